// Round 11
// baseline (1590.034 us; speedup 1.0000x reference)
//
#include <hip/hip_runtime.h>
#include <hip/hip_bf16.h>
#include <stdint.h>

// ---------------------------------------------------------------------------
// PFGAT: [B,T,N,F]=[4,8,2048,16] transformer (causal attn over N per (b,t),
// node attn over T-slots, MLP at last slot) -> 2x GATConv -> FFN -> [B,14,N].
// fp32 I/O, fp32 compute, bf16 intermediate storage.
// R11: MFMA flash attn WITHOUT online-max (softmax shift-invariance; scores
// are O(1) so exp can't overflow): K-loop has zero cross-lane ops and no
// cross-step softmax dependency -> steps overlap, latency hidden.
// ---------------------------------------------------------------------------

#define BB     4
#define TT     8
#define NN     2048
#define FIN    16
#define HID    128
#define BM     (BB*TT)            // 32 attention slices
#define PROWS  (BM*NN)            // 65536 rows
#define NHEADS 4
#define OUTCH  64
#define OUTF   14
#define NEDGE  32768
#define NEDGEB (NEDGE*BB)         // 131072
#define NNODE  (BB*NN)            // 8192
#define NETOT  (NEDGEB + NNODE)   // 139264 (edges + self loops)

#define TQ     64                 // query tile (rows per block)
#define NTILE  (NN/TQ)            // 32 query tiles per slice

typedef __hip_bfloat16 bf16;
typedef __attribute__((ext_vector_type(8))) short bf16x8;   // MFMA A/B frag
typedef __attribute__((ext_vector_type(4))) float f32x4;    // MFMA C/D frag

__device__ __forceinline__ float b2f(bf16 v){ return __bfloat162float(v); }
__device__ __forceinline__ bf16  f2b(float f){ return __float2bfloat16(f); }

// ---------------------------------------------------------------------------
// K1: per row: LN1 over F=16 -> k,v projections; K row-major, V transposed
// (Vt[slice][ch][key]) for MFMA B-fragment contiguity.
// ---------------------------------------------------------------------------
__global__ void k_kv(const float* __restrict__ x,
                     const float* __restrict__ g1, const float* __restrict__ bb1,
                     const float* __restrict__ wk, const float* __restrict__ bk,
                     const float* __restrict__ wv, const float* __restrict__ bv,
                     int in_off, bf16* __restrict__ K, bf16* __restrict__ Vt)
{
    const int rloc = blockIdx.x;
    const int rin  = rloc + in_off;
    const int h = threadIdx.x;       // 0..127
    __shared__ float xr[FIN], lnv[FIN];
    if (h < FIN) xr[h] = x[(size_t)rin*FIN + h];
    __syncthreads();
    float mu = 0.f;
    #pragma unroll
    for (int f = 0; f < FIN; ++f) mu += xr[f];
    mu *= (1.f/FIN);
    float var = 0.f;
    #pragma unroll
    for (int f = 0; f < FIN; ++f){ float d = xr[f]-mu; var += d*d; }
    var *= (1.f/FIN);
    const float inv = rsqrtf(var + 1e-5f);
    if (h < FIN) lnv[h] = (xr[h]-mu)*inv*g1[h] + bb1[h];
    __syncthreads();
    float ak = bk[h], av = bv[h];
    #pragma unroll
    for (int f = 0; f < FIN; ++f){
        const float l = lnv[f];
        ak += l * wk[f*HID + h];
        av += l * wv[f*HID + h];
    }
    K[(size_t)rloc*HID + h] = f2b(ak);
    const int slice = rloc >> 11;            // 0 in narrow mode
    const int key   = rloc & (NN-1);
    Vt[((size_t)slice*HID + h)*NN + key] = f2b(av);
}

// ---------------------------------------------------------------------------
// K2 (MFMA flash, no-max softmax): block = one 64-row Q tile; 4 waves, wave
// w owns rows 16w..16w+15. Per 32-key step: S = Q.K^T (8 MFMAs, K B-frags
// 16B global), mask + exp (per-lane only), P -> LDS (C-layout write,
// A-layout b128 read), PV (8 MFMAs, Vt B-frags). l accumulated per-lane,
// reduced once after the loop. No barriers / no cross-lane in K-loop.
// ---------------------------------------------------------------------------
__global__ __launch_bounds__(256)
void k_attn_mfma(const float* __restrict__ x,
                 const bf16* __restrict__ K, const bf16* __restrict__ Vt,
                 const float* __restrict__ g1, const float* __restrict__ bb1,
                 const float* __restrict__ wq, const float* __restrict__ bq,
                 const float* __restrict__ skw, const float* __restrict__ skb,
                 const float* __restrict__ t_wo, const float* __restrict__ t_bo,
                 int slice_off, bf16* __restrict__ H1)
{
    const int tile  = (NTILE-1) - (int)blockIdx.x;   // big tiles first
    const int q0    = tile*TQ;
    const int slice = blockIdx.y + slice_off;
    const int t     = threadIdx.x;
    const int w     = t >> 6;            // wave 0..3
    const int lane  = t & 63;
    const int quad  = lane >> 4;
    const int l16   = lane & 15;
    const int wr0   = w*16;              // wave's first local row

    __shared__ float xs [TQ][FIN];                 // raw x rows (skip)
    __shared__ float lns[TQ][FIN];                 // LN1(x) rows
    __shared__ bf16  Qs [TQ][136];                 // Q (scaled) bf16; cx later
    __shared__ bf16  Ps [4][16][40];               // per-wave P roundtrip

    // ---- stage x rows ----
    for (int u = t; u < TQ*FIN; u += 256)
        ((float*)xs)[u] = x[((size_t)slice*NN + q0)*FIN + u];
    __syncthreads();
    // ---- LN1 per row ----
    if (t < TQ){
        float mu = 0.f;
        #pragma unroll
        for (int f = 0; f < FIN; ++f) mu += xs[t][f];
        mu *= (1.f/FIN);
        float var = 0.f;
        #pragma unroll
        for (int f = 0; f < FIN; ++f){ float d = xs[t][f]-mu; var += d*d; }
        var *= (1.f/FIN);
        const float inv = rsqrtf(var + 1e-5f);
        #pragma unroll
        for (int f = 0; f < FIN; ++f)
            lns[t][f] = (xs[t][f]-mu)*inv*g1[f] + bb1[f];
    }
    __syncthreads();
    // ---- Q (scale folded) -> Qs bf16 ----
    {
        const int r = t >> 2, c0 = (t & 3)*32;
        const float scale = 0.08838834764831845f;   // 1/sqrt(128)
        #pragma unroll
        for (int k = 0; k < 32; ++k){
            const int ch = c0 + k;
            float a = bq[ch];
            #pragma unroll
            for (int f = 0; f < FIN; ++f) a += lns[r][f]*wq[f*HID + ch];
            Qs[r][ch] = f2b(a*scale);
        }
    }
    __syncthreads();

    // ---- Q A-frags: A[m=l16][k=quad*8+j], k-step ks*32 ----
    bf16x8 qf[4];
    #pragma unroll
    for (int ks = 0; ks < 4; ++ks)
        qf[ks] = *(const bf16x8*)(const void*)&Qs[wr0 + l16][ks*32 + quad*8];

    f32x4 O[8];
    #pragma unroll
    for (int ct = 0; ct < 8; ++ct) O[ct] = (f32x4){0.f,0.f,0.f,0.f};
    float l_[4] = {0.f,0.f,0.f,0.f};     // per-lane partial row sums

    const size_t kb = (size_t)blockIdx.y * NN * HID;            // K slice base
    const size_t vb = (size_t)blockIdx.y * (size_t)HID * NN;    // Vt slice base
    const int jend = q0 + wr0 + 15;         // wave-uniform causal bound
    const int brow = q0 + wr0 + quad*4;     // +reg = my global q-row

    for (int j0 = 0; j0 <= jend; j0 += 32){
        // ---- S tiles: cols j0..j0+15 (S0) and j0+16..j0+31 (S1) ----
        f32x4 S0 = (f32x4){0.f,0.f,0.f,0.f}, S1 = S0;
        #pragma unroll
        for (int ks = 0; ks < 4; ++ks){
            const bf16x8 kf0 = *(const bf16x8*)(const void*)
                (K + kb + (size_t)(j0      + l16)*HID + ks*32 + quad*8);
            const bf16x8 kf1 = *(const bf16x8*)(const void*)
                (K + kb + (size_t)(j0 + 16 + l16)*HID + ks*32 + quad*8);
            S0 = __builtin_amdgcn_mfma_f32_16x16x32_bf16(qf[ks], kf0, S0, 0, 0, 0);
            S1 = __builtin_amdgcn_mfma_f32_16x16x32_bf16(qf[ks], kf1, S1, 0, 0, 0);
        }
        // ---- mask + exp (shift-free softmax numerator; |s| ~ O(1)) ----
        const int c0j = j0 + l16, c1j = c0j + 16;
        #pragma unroll
        for (int r = 0; r < 4; ++r){
            const float s0 = (c0j <= brow + r) ? S0[r] : -1e30f;
            const float s1 = (c1j <= brow + r) ? S1[r] : -1e30f;
            const bf16 hb0 = f2b(__expf(s0));
            const bf16 hb1 = f2b(__expf(s1));
            Ps[w][quad*4 + r][l16]      = hb0;
            Ps[w][quad*4 + r][l16 + 16] = hb1;
            l_[r] += b2f(hb0) + b2f(hb1);       // sum the rounded P
        }
        // ---- PV: A = P (A-layout via LDS), B = Vt frags ----
        const bf16x8 pf = *(const bf16x8*)(const void*)&Ps[w][l16][quad*8];
        #pragma unroll
        for (int ct = 0; ct < 8; ++ct){
            const bf16x8 vf = *(const bf16x8*)(const void*)
                (Vt + vb + (size_t)(ct*16 + l16)*NN + j0 + quad*8);
            O[ct] = __builtin_amdgcn_mfma_f32_16x16x32_bf16(pf, vf, O[ct], 0, 0, 0);
        }
    }

    // ---- reduce l across the 16 key-lanes (once), normalize -> cx ----
    {
        float inv[4];
        #pragma unroll
        for (int r = 0; r < 4; ++r){
            float rs = l_[r];
            rs += __shfl_xor(rs, 1);
            rs += __shfl_xor(rs, 2);
            rs += __shfl_xor(rs, 4);
            rs += __shfl_xor(rs, 8);
            inv[r] = 1.f/rs;
        }
        #pragma unroll
        for (int ct = 0; ct < 8; ++ct)
        #pragma unroll
        for (int r = 0; r < 4; ++r)
            Qs[wr0 + quad*4 + r][ct*16 + l16] = f2b(O[ct][r]*inv[r]);
    }
    // ---- epilogue: rows t>>2 belong to this thread's wave -> no barrier ----
    {
        const int row = t >> 2, ch0 = (t & 3)*32;
        float outv[32];
        #pragma unroll
        for (int k = 0; k < 32; ++k){
            const int ch = ch0 + k;
            float a = t_bo[ch] + skb[ch];
            #pragma unroll
            for (int f = 0; f < FIN; ++f) a += xs[row][f]*skw[f*HID + ch];
            outv[k] = a;
        }
        for (int cc = 0; cc < HID; ++cc){
            const int c = (cc + 2*row) & (HID-1);
            const float cxv = b2f(Qs[row][c]);
            #pragma unroll
            for (int k = 0; k < 32; ++k) outv[k] += cxv * t_wo[c*HID + ch0 + k];
        }
        #pragma unroll
        for (int k = 0; k < 32; ++k)
            H1[((size_t)slice*NN + q0 + row)*HID + ch0 + k] = f2b(outv[k]);
    }
}

// ---------------------------------------------------------------------------
// K3: per (b,s): load h1[m] (all 8 m), LN2, node attention (q for m=7 only),
// LN3, MLP -> node feature [128] fp32.
// ---------------------------------------------------------------------------
__global__ void k_mix(const bf16* __restrict__ H1,
                      const float* __restrict__ ln2g, const float* __restrict__ ln2b,
                      const float* __restrict__ s_wq, const float* __restrict__ s_bq,
                      const float* __restrict__ s_wk, const float* __restrict__ s_bk,
                      const float* __restrict__ s_wv, const float* __restrict__ s_bv,
                      const float* __restrict__ s_wo, const float* __restrict__ s_bo,
                      const float* __restrict__ ln3g, const float* __restrict__ ln3b,
                      const float* __restrict__ w1, const float* __restrict__ bm1,
                      const float* __restrict__ w2, const float* __restrict__ bm2,
                      float* __restrict__ Hn)
{
    const int blk = blockIdx.x;          // b*NN + s
    const int b = blk >> 11, s = blk & (NN-1);
    const int h = threadIdx.x;           // 0..127
    __shared__ float h1[TT][HID], z2[TT][HID], k2[TT][HID], v2[TT][HID];
    __shared__ float qv[HID], z3s[HID], hls[2*HID];
    __shared__ float scr[TT];
    __shared__ float rb1[HID], rb2[HID];

    #pragma unroll
    for (int m = 0; m < TT; ++m)
        h1[m][h] = b2f(H1[((size_t)(b*TT + m)*NN + s)*HID + h]);
    __syncthreads();

    const float g2v = ln2g[h], b2v = ln2b[h];
    for (int m = 0; m < TT; ++m){
        const float v = h1[m][h];
        rb1[h] = v; rb2[h] = v*v; __syncthreads();
        for (int st = 64; st > 0; st >>= 1){
            if (h < st){ rb1[h] += rb1[h+st]; rb2[h] += rb2[h+st]; }
            __syncthreads();
        }
        const float mu = rb1[0]*(1.f/HID);
        const float var = rb2[0]*(1.f/HID) - mu*mu;
        const float inv = rsqrtf(var + 1e-5f);
        __syncthreads();
        z2[m][h] = (v - mu)*inv*g2v + b2v;
    }
    __syncthreads();

    {
        float ack[TT], acv[TT];
        const float bkv = s_bk[h], bvv = s_bv[h];
        #pragma unroll
        for (int m = 0; m < TT; ++m){ ack[m] = bkv; acv[m] = bvv; }
        for (int c = 0; c < HID; ++c){
            const float wk = s_wk[c*HID + h];
            const float wv = s_wv[c*HID + h];
            #pragma unroll
            for (int m = 0; m < TT; ++m){ ack[m] += z2[m][c]*wk; acv[m] += z2[m][c]*wv; }
        }
        #pragma unroll
        for (int m = 0; m < TT; ++m){ k2[m][h] = ack[m]; v2[m][h] = acv[m]; }
        float aq = s_bq[h];
        for (int c = 0; c < HID; ++c) aq += z2[TT-1][c]*s_wq[c*HID + h];
        qv[h] = aq;
    }
    __syncthreads();

    if (h < TT){
        float d = 0.f;
        for (int c = 0; c < HID; ++c) d += qv[c]*k2[h][c];
        scr[h] = d * 0.08838834764831845f;
    }
    __syncthreads();
    float mx = -1e30f;
    #pragma unroll
    for (int m = 0; m < TT; ++m) mx = fmaxf(mx, scr[m]);
    float p[TT], se = 0.f;
    #pragma unroll
    for (int m = 0; m < TT; ++m){ p[m] = __expf(scr[m]-mx); se += p[m]; }
    const float isum = 1.f/se;
    float c2 = 0.f;
    #pragma unroll
    for (int m = 0; m < TT; ++m) c2 += p[m]*v2[m][h];
    c2 *= isum;
    __syncthreads();
    qv[h] = c2;
    __syncthreads();

    float o = s_bo[h];
    for (int c = 0; c < HID; ++c) o += qv[c]*s_wo[c*HID + h];
    const float h2 = h1[TT-1][h] + o;

    rb1[h] = h2; rb2[h] = h2*h2; __syncthreads();
    for (int st = 64; st > 0; st >>= 1){
        if (h < st){ rb1[h] += rb1[h+st]; rb2[h] += rb2[h+st]; }
        __syncthreads();
    }
    {
        const float mu = rb1[0]*(1.f/HID);
        const float var = rb2[0]*(1.f/HID) - mu*mu;
        const float inv = rsqrtf(var + 1e-5f);
        __syncthreads();
        z3s[h] = (h2 - mu)*inv*ln3g[h] + ln3b[h];
    }
    __syncthreads();

    float hid0 = bm1[h], hid1 = bm1[h+HID];
    for (int c = 0; c < HID; ++c){
        const float z = z3s[c];
        hid0 += z * w1[c*2*HID + h];
        hid1 += z * w1[c*2*HID + h + HID];
    }
    hls[h] = fmaxf(hid0, 0.f); hls[h+HID] = fmaxf(hid1, 0.f);
    __syncthreads();
    float outv = bm2[h] + h2;
    for (int j = 0; j < 2*HID; ++j) outv += hls[j]*w2[j*HID + h];
    Hn[(size_t)(b*NN + s)*HID + h] = outv;
}

// ---------------------------------------------------------------------------
// GAT
// ---------------------------------------------------------------------------
__device__ __forceinline__ void edge_decode(const int* __restrict__ ei, int e,
                                            int& src, int& dst, bool& dropped)
{
    if (e < NEDGEB){
        const int bb = e >> 15, k = e & (NEDGE-1);
        const int s0 = ei[k], d0 = ei[NEDGE + k];
        src = s0 + bb*NN; dst = d0 + bb*NN;
        dropped = (s0 == d0);     // PyG removes pre-existing self loops
    } else { src = dst = e - NEDGEB; dropped = false; }
}

__global__ void k_gat1_lin(const float* __restrict__ Hn, const float* __restrict__ W,
                           const float* __restrict__ asrc, const float* __restrict__ adst,
                           bf16* __restrict__ hw, float* __restrict__ als, float* __restrict__ ald)
{
    const int nid = blockIdx.x, c = threadIdx.x;   // 128
    __shared__ float hr[HID], r1[HID], r2[HID];
    hr[c] = Hn[(size_t)nid*HID + c];
    __syncthreads();
    float a = 0.f;
    for (int k = 0; k < HID; ++k) a += hr[k]*W[k*HID + c];
    hw[(size_t)nid*HID + c] = f2b(a);
    r1[c] = a*asrc[c]; r2[c] = a*adst[c];
    __syncthreads();
    for (int st = 16; st > 0; st >>= 1){
        if ((c & 31) < st){ r1[c] += r1[c+st]; r2[c] += r2[c+st]; }
        __syncthreads();
    }
    if ((c & 31) == 0){
        als[nid*NHEADS + (c>>5)] = r1[c];
        ald[nid*NHEADS + (c>>5)] = r2[c];
    }
}

__global__ void k_gat_edge1(const int* __restrict__ ei, const float* __restrict__ als,
                            const float* __restrict__ ald, bf16* __restrict__ ex,
                            float* __restrict__ denom)
{
    const int idx = blockIdx.x*blockDim.x + threadIdx.x;
    if (idx >= NETOT*NHEADS) return;
    const int e = idx >> 2, hd = idx & 3;
    int src, dst; bool drop;
    edge_decode(ei, e, src, dst, drop);
    if (drop){ ex[idx] = f2b(0.f); return; }
    float a = als[src*NHEADS + hd] + ald[dst*NHEADS + hd];
    a = a > 0.f ? a : 0.2f*a;
    const bf16 vb = f2b(__expf(a));
    ex[idx] = vb;
    atomicAdd(&denom[dst*NHEADS + hd], b2f(vb));
}

__global__ void k_gat_agg1(const int* __restrict__ ei, const bf16* __restrict__ ex,
                           const float* __restrict__ denom, const bf16* __restrict__ hw,
                           float* __restrict__ agg)
{
    const int t = blockIdx.x*blockDim.x + threadIdx.x;   // NETOT*128
    const int e = t >> 7, c = t & 127;
    if (e >= NETOT) return;
    const float x = b2f(ex[e*NHEADS + (c>>5)]);
    if (x == 0.f) return;
    int src, dst; bool drop;
    edge_decode(ei, e, src, dst, drop);
    const float w = x / denom[dst*NHEADS + (c>>5)];
    atomicAdd(&agg[(size_t)dst*HID + c], w * b2f(hw[(size_t)src*HID + c]));
}

__global__ void k_gat1_fin(const float* __restrict__ agg, const float* __restrict__ bias,
                           bf16* __restrict__ g1)
{
    const int t = blockIdx.x*blockDim.x + threadIdx.x;
    if (t >= NNODE*HID) return;
    const float v = agg[t] + bias[t & 127];
    g1[t] = f2b(v > 0.f ? v : expm1f(v));    // elu
}

__global__ void k_gat2_lin(const bf16* __restrict__ g1, const float* __restrict__ W,
                           const float* __restrict__ asrc, const float* __restrict__ adst,
                           bf16* __restrict__ hw2, float* __restrict__ al2s, float* __restrict__ al2d)
{
    const int nid = blockIdx.x, c = threadIdx.x;    // 64 threads = 1 wave
    __shared__ float hr[HID];
    hr[c] = b2f(g1[(size_t)nid*HID + c]);
    hr[c+64] = b2f(g1[(size_t)nid*HID + c + 64]);
    __syncthreads();
    float a = 0.f;
    for (int k = 0; k < HID; ++k) a += hr[k]*W[k*OUTCH + c];
    hw2[(size_t)nid*OUTCH + c] = f2b(a);
    float s1 = a*asrc[c], s2 = a*adst[c];
    #pragma unroll
    for (int off = 32; off > 0; off >>= 1){
        s1 += __shfl_down(s1, off);
        s2 += __shfl_down(s2, off);
    }
    if (c == 0){ al2s[nid] = s1; al2d[nid] = s2; }
}

__global__ void k_gat_edge2(const int* __restrict__ ei, const float* __restrict__ als,
                            const float* __restrict__ ald, bf16* __restrict__ ex,
                            float* __restrict__ denom)
{
    const int e = blockIdx.x*blockDim.x + threadIdx.x;
    if (e >= NETOT) return;
    int src, dst; bool drop;
    edge_decode(ei, e, src, dst, drop);
    if (drop){ ex[e] = f2b(0.f); return; }
    float a = als[src] + ald[dst];
    a = a > 0.f ? a : 0.2f*a;
    const bf16 vb = f2b(__expf(a));
    ex[e] = vb;
    atomicAdd(&denom[dst], b2f(vb));
}

__global__ void k_gat_agg2(const int* __restrict__ ei, const bf16* __restrict__ ex,
                           const float* __restrict__ denom, const bf16* __restrict__ hw2,
                           float* __restrict__ agg)
{
    const int t = blockIdx.x*blockDim.x + threadIdx.x;   // NETOT*64
    const int e = t >> 6, c = t & 63;
    if (e >= NETOT) return;
    const float x = b2f(ex[e]);
    if (x == 0.f) return;
    int src, dst; bool drop;
    edge_decode(ei, e, src, dst, drop);
    const float w = x / denom[dst];
    atomicAdd(&agg[(size_t)dst*OUTCH + c], w * b2f(hw2[(size_t)src*OUTCH + c]));
}

__global__ void k_final(const float* __restrict__ agg2, const float* __restrict__ g2b,
                        const float* __restrict__ fw, const float* __restrict__ fb,
                        float* __restrict__ out)
{
    const int nid = blockIdx.x, c = threadIdx.x;    // 64
    __shared__ float g[OUTCH];
    g[c] = agg2[(size_t)nid*OUTCH + c] + g2b[c];
    __syncthreads();
    if (c < OUTF){
        float o = fb[c];
        for (int k = 0; k < OUTCH; ++k) o += g[k]*fw[k*OUTF + c];
        const int b = nid >> 11, n = nid & (NN-1);
        out[((size_t)b*OUTF + c)*NN + n] = o;
    }
}

// ---------------------------------------------------------------------------
extern "C" void kernel_launch(void* const* d_in, const int* in_sizes, int n_in,
                              void* d_out, int out_size, void* d_ws, size_t ws_size,
                              hipStream_t stream)
{
    const float* x    = (const float*)d_in[0];
    const int*  ei    = (const int*)d_in[1];
    const float* ln1g = (const float*)d_in[2];  const float* ln1b = (const float*)d_in[3];
    const float* t_wq = (const float*)d_in[4];  const float* t_bq = (const float*)d_in[5];
    const float* t_wk = (const float*)d_in[6];  const float* t_bk = (const float*)d_in[7];
    const float* t_wv = (const float*)d_in[8];  const float* t_bv = (const float*)d_in[9];
    const float* t_wo = (const float*)d_in[10]; const float* t_bo = (const float*)d_in[11];
    const float* skw  = (const float*)d_in[12]; const float* skb  = (const float*)d_in[13];
    const float* ln2g = (const float*)d_in[14]; const float* ln2b = (const float*)d_in[15];
    const float* s_wq = (const float*)d_in[16]; const float* s_bq = (const float*)d_in[17];
    const float* s_wk = (const float*)d_in[18]; const float* s_bk = (const float*)d_in[19];
    const float* s_wv = (const float*)d_in[20]; const float* s_bv = (const float*)d_in[21];
    const float* s_wo = (const float*)d_in[22]; const float* s_bo = (const float*)d_in[23];
    const float* ln3g = (const float*)d_in[24]; const float* ln3b = (const float*)d_in[25];
    const float* w1   = (const float*)d_in[26]; const float* b1   = (const float*)d_in[27];
    const float* w2   = (const float*)d_in[28]; const float* b2   = (const float*)d_in[29];
    const float* g1w  = (const float*)d_in[30];
    const float* g1as = (const float*)d_in[31]; const float* g1ad = (const float*)d_in[32];
    const float* g1b  = (const float*)d_in[33];
    const float* g2w  = (const float*)d_in[34];
    const float* g2as = (const float*)d_in[35]; const float* g2ad = (const float*)d_in[36];
    const float* g2b  = (const float*)d_in[37];
    const float* ffw  = (const float*)d_in[38]; const float* ffb  = (const float*)d_in[39];
    float* out = (float*)d_out;

    const size_t MiB = 1024u*1024u;
    const bool wide = ws_size >= 52*MiB;   // K(16)+Vt(16)+H1(16)+Hn(4)

    char* base = (char*)d_ws;
    bf16 *Kb, *Vtb, *H1;
    float* Hn;
    char* gat_base;
    if (wide){
        Kb  = (bf16*)(base + 0*MiB);       // 16 MiB (all 32 slices, row-major)
        Vtb = (bf16*)(base + 16*MiB);      // 16 MiB ([slice][ch][key])
        H1  = (bf16*)(base + 32*MiB);      // 16 MiB
        Hn  = (float*)(base + 48*MiB);     // 4 MiB
        gat_base = base;                   // aliases Kb/Vtb (dead after attn)
    } else {
        H1  = (bf16*)(base + 0*MiB);       // 16 MiB
        Hn  = (float*)(base + 16*MiB);     // 4 MiB
        Kb  = (bf16*)(base + 20*MiB);      // 0.5 MiB (one slice)
        Vtb = (bf16*)(base + 20*MiB + 512u*1024u);
        gat_base = base;                   // aliases H1 (dead after k_mix)
    }
    // GAT scratch (~12.9 MiB) inside gat_base
    char* w = gat_base;
    auto alloc = [&](size_t bytes){ void* p = (void*)w; w += (bytes + 255) & ~(size_t)255; return p; };
    bf16*  hw1  = (bf16*) alloc((size_t)NNODE*HID*sizeof(bf16));
    float* als1 = (float*)alloc((size_t)NNODE*NHEADS*sizeof(float));
    float* ald1 = (float*)alloc((size_t)NNODE*NHEADS*sizeof(float));
    bf16*  ex1  = (bf16*) alloc((size_t)NETOT*NHEADS*sizeof(bf16));
    float* den1 = (float*)alloc((size_t)NNODE*NHEADS*sizeof(float));
    float* agg1 = (float*)alloc((size_t)NNODE*HID*sizeof(float));
    bf16*  g1o  = (bf16*) alloc((size_t)NNODE*HID*sizeof(bf16));
    bf16*  hw2  = (bf16*) alloc((size_t)NNODE*OUTCH*sizeof(bf16));
    float* als2 = (float*)alloc((size_t)NNODE*sizeof(float));
    float* ald2 = (float*)alloc((size_t)NNODE*sizeof(float));
    bf16*  ex2  = (bf16*) alloc((size_t)NETOT*sizeof(bf16));
    float* den2 = (float*)alloc((size_t)NNODE*sizeof(float));
    float* agg2 = (float*)alloc((size_t)NNODE*OUTCH*sizeof(float));

    // ---- trunk ----
    if (wide){
        k_kv<<<PROWS, HID, 0, stream>>>(x, ln1g, ln1b, t_wk, t_bk, t_wv, t_bv, 0, Kb, Vtb);
        k_attn_mfma<<<dim3(NTILE, BM), 256, 0, stream>>>(x, Kb, Vtb, ln1g, ln1b, t_wq, t_bq,
                                                         skw, skb, t_wo, t_bo, 0, H1);
    } else {
        for (int s = 0; s < BM; ++s){
            k_kv<<<NN, HID, 0, stream>>>(x, ln1g, ln1b, t_wk, t_bk, t_wv, t_bv, s*NN, Kb, Vtb);
            k_attn_mfma<<<dim3(NTILE, 1), 256, 0, stream>>>(x, Kb, Vtb, ln1g, ln1b, t_wq, t_bq,
                                                            skw, skb, t_wo, t_bo, s, H1);
        }
    }
    k_mix<<<BB*NN, HID, 0, stream>>>(H1, ln2g, ln2b, s_wq, s_bq, s_wk, s_bk,
                                     s_wv, s_bv, s_wo, s_bo, ln3g, ln3b,
                                     w1, b1, w2, b2, Hn);

    // ---- GAT (accumulators zeroed after k_mix; region was dead/poisoned) ----
    hipMemsetAsync(den1, 0, (size_t)NNODE*NHEADS*sizeof(float), stream);
    hipMemsetAsync(agg1, 0, (size_t)NNODE*HID*sizeof(float), stream);
    hipMemsetAsync(den2, 0, (size_t)NNODE*sizeof(float), stream);
    hipMemsetAsync(agg2, 0, (size_t)NNODE*OUTCH*sizeof(float), stream);

    k_gat1_lin<<<NNODE, HID, 0, stream>>>(Hn, g1w, g1as, g1ad, hw1, als1, ald1);
    k_gat_edge1<<<(NETOT*NHEADS + 255)/256, 256, 0, stream>>>(ei, als1, ald1, ex1, den1);
    k_gat_agg1<<<(NETOT*HID)/256, 256, 0, stream>>>(ei, ex1, den1, hw1, agg1);
    k_gat1_fin<<<(NNODE*HID)/256, 256, 0, stream>>>(agg1, g1b, g1o);
    k_gat2_lin<<<NNODE, OUTCH, 0, stream>>>(g1o, g2w, g2as, g2ad, hw2, als2, ald2);
    k_gat_edge2<<<(NETOT + 255)/256, 256, 0, stream>>>(ei, als2, ald2, ex2, den2);
    k_gat_agg2<<<(NETOT*OUTCH)/256, 256, 0, stream>>>(ei, ex2, den2, hw2, agg2);
    k_final<<<NNODE, OUTCH, 0, stream>>>(agg2, g2b, ffw, ffb, out);
}

// Round 12
// 1323.108 us; speedup vs baseline: 1.2017x; 1.2017x over previous
//
#include <hip/hip_runtime.h>
#include <hip/hip_bf16.h>
#include <stdint.h>

// ---------------------------------------------------------------------------
// PFGAT: [B,T,N,F]=[4,8,2048,16] transformer (causal attn over N per (b,t),
// node attn over T-slots, MLP at last slot) -> 2x GATConv -> FFN -> [B,14,N].
// fp32 I/O, fp32 compute, bf16 intermediate storage.
// R12: MFMA flash attn + XCD-aware swizzle (blockIdx.x = slice -> each XCD
// keeps its 4 slices' K/Vt = 4MB resident in L2) + batched kf/vf loads
// (one vmcnt drain per group instead of per-pair serialization).
// ---------------------------------------------------------------------------

#define BB     4
#define TT     8
#define NN     2048
#define FIN    16
#define HID    128
#define BM     (BB*TT)            // 32 attention slices
#define PROWS  (BM*NN)            // 65536 rows
#define NHEADS 4
#define OUTCH  64
#define OUTF   14
#define NEDGE  32768
#define NEDGEB (NEDGE*BB)         // 131072
#define NNODE  (BB*NN)            // 8192
#define NETOT  (NEDGEB + NNODE)   // 139264 (edges + self loops)

#define TQ     64                 // query tile (rows per block)
#define NTILE  (NN/TQ)            // 32 query tiles per slice

typedef __hip_bfloat16 bf16;
typedef __attribute__((ext_vector_type(8))) short bf16x8;   // MFMA A/B frag
typedef __attribute__((ext_vector_type(4))) float f32x4;    // MFMA C/D frag

__device__ __forceinline__ float b2f(bf16 v){ return __bfloat162float(v); }
__device__ __forceinline__ bf16  f2b(float f){ return __float2bfloat16(f); }

// ---------------------------------------------------------------------------
// K1: per row: LN1 over F=16 -> k,v projections; K row-major, V transposed
// (Vt[slice][ch][key]) for MFMA B-fragment contiguity.
// ---------------------------------------------------------------------------
__global__ void k_kv(const float* __restrict__ x,
                     const float* __restrict__ g1, const float* __restrict__ bb1,
                     const float* __restrict__ wk, const float* __restrict__ bk,
                     const float* __restrict__ wv, const float* __restrict__ bv,
                     int in_off, bf16* __restrict__ K, bf16* __restrict__ Vt)
{
    const int rloc = blockIdx.x;
    const int rin  = rloc + in_off;
    const int h = threadIdx.x;       // 0..127
    __shared__ float xr[FIN], lnv[FIN];
    if (h < FIN) xr[h] = x[(size_t)rin*FIN + h];
    __syncthreads();
    float mu = 0.f;
    #pragma unroll
    for (int f = 0; f < FIN; ++f) mu += xr[f];
    mu *= (1.f/FIN);
    float var = 0.f;
    #pragma unroll
    for (int f = 0; f < FIN; ++f){ float d = xr[f]-mu; var += d*d; }
    var *= (1.f/FIN);
    const float inv = rsqrtf(var + 1e-5f);
    if (h < FIN) lnv[h] = (xr[h]-mu)*inv*g1[h] + bb1[h];
    __syncthreads();
    float ak = bk[h], av = bv[h];
    #pragma unroll
    for (int f = 0; f < FIN; ++f){
        const float l = lnv[f];
        ak += l * wk[f*HID + h];
        av += l * wv[f*HID + h];
    }
    K[(size_t)rloc*HID + h] = f2b(ak);
    const int slice = rloc >> 11;            // 0 in narrow mode
    const int key   = rloc & (NN-1);
    Vt[((size_t)slice*HID + h)*NN + key] = f2b(av);
}

// ---------------------------------------------------------------------------
// K2 (MFMA flash): blockIdx.x = slice (XCD-stable: slice s -> XCD s%8, so
// each XCD's 4 slices' K/Vt (4MB) stay L2-resident), blockIdx.y = tile rank
// (0 = biggest, LPT). 4 waves, wave w owns rows 16w..16w+15. Per 32-key
// step: kf[8] batch-loaded (one vmcnt drain), S = Q.K^T (8 MFMAs), vf[8]
// batch issued so latency hides under exp/Ps/lgkmcnt, P via LDS roundtrip,
// PV (8 MFMAs). No-max softmax (scores O(1)); l reduced once at the end.
// ---------------------------------------------------------------------------
__global__ __launch_bounds__(256)
void k_attn_mfma(const float* __restrict__ x,
                 const bf16* __restrict__ K, const bf16* __restrict__ Vt,
                 const float* __restrict__ g1, const float* __restrict__ bb1,
                 const float* __restrict__ wq, const float* __restrict__ bq,
                 const float* __restrict__ skw, const float* __restrict__ skb,
                 const float* __restrict__ t_wo, const float* __restrict__ t_bo,
                 int slice_off, bf16* __restrict__ H1)
{
    const int tile  = (NTILE-1) - (int)blockIdx.y;   // big tiles first
    const int q0    = tile*TQ;
    const int slice = blockIdx.x + slice_off;
    const int t     = threadIdx.x;
    const int w     = t >> 6;            // wave 0..3
    const int lane  = t & 63;
    const int quad  = lane >> 4;
    const int l16   = lane & 15;
    const int wr0   = w*16;              // wave's first local row

    __shared__ float xs [TQ][FIN];                 // raw x rows (skip)
    __shared__ float lns[TQ][FIN];                 // LN1(x) rows
    __shared__ bf16  Qs [TQ][136];                 // Q (scaled) bf16; cx later
    __shared__ bf16  Ps [4][16][40];               // per-wave P roundtrip

    // ---- stage x rows ----
    for (int u = t; u < TQ*FIN; u += 256)
        ((float*)xs)[u] = x[((size_t)slice*NN + q0)*FIN + u];
    __syncthreads();
    // ---- LN1 per row ----
    if (t < TQ){
        float mu = 0.f;
        #pragma unroll
        for (int f = 0; f < FIN; ++f) mu += xs[t][f];
        mu *= (1.f/FIN);
        float var = 0.f;
        #pragma unroll
        for (int f = 0; f < FIN; ++f){ float d = xs[t][f]-mu; var += d*d; }
        var *= (1.f/FIN);
        const float inv = rsqrtf(var + 1e-5f);
        #pragma unroll
        for (int f = 0; f < FIN; ++f)
            lns[t][f] = (xs[t][f]-mu)*inv*g1[f] + bb1[f];
    }
    __syncthreads();
    // ---- Q (scale folded) -> Qs bf16 ----
    {
        const int r = t >> 2, c0 = (t & 3)*32;
        const float scale = 0.08838834764831845f;   // 1/sqrt(128)
        #pragma unroll
        for (int k = 0; k < 32; ++k){
            const int ch = c0 + k;
            float a = bq[ch];
            #pragma unroll
            for (int f = 0; f < FIN; ++f) a += lns[r][f]*wq[f*HID + ch];
            Qs[r][ch] = f2b(a*scale);
        }
    }
    __syncthreads();

    // ---- Q A-frags: A[m=l16][k=quad*8+j], k-step ks*32 ----
    bf16x8 qf[4];
    #pragma unroll
    for (int ks = 0; ks < 4; ++ks)
        qf[ks] = *(const bf16x8*)(const void*)&Qs[wr0 + l16][ks*32 + quad*8];

    f32x4 O[8];
    #pragma unroll
    for (int ct = 0; ct < 8; ++ct) O[ct] = (f32x4){0.f,0.f,0.f,0.f};
    float l_[4] = {0.f,0.f,0.f,0.f};     // per-lane partial row sums

    const size_t kb = (size_t)blockIdx.x * NN * HID;            // K slice base
    const size_t vb = (size_t)blockIdx.x * (size_t)HID * NN;    // Vt slice base
    const int jend = q0 + wr0 + 15;         // wave-uniform causal bound
    const int brow = q0 + wr0 + quad*4;     // +reg = my global q-row

    for (int j0 = 0; j0 <= jend; j0 += 32){
        // ---- kf batch: 8 loads in flight, one drain ----
        bf16x8 kf[8];
        #pragma unroll
        for (int ks = 0; ks < 4; ++ks){
            kf[2*ks]   = *(const bf16x8*)(const void*)
                (K + kb + (size_t)(j0      + l16)*HID + ks*32 + quad*8);
            kf[2*ks+1] = *(const bf16x8*)(const void*)
                (K + kb + (size_t)(j0 + 16 + l16)*HID + ks*32 + quad*8);
        }
        // ---- S tiles ----
        f32x4 S0 = (f32x4){0.f,0.f,0.f,0.f}, S1 = S0;
        #pragma unroll
        for (int ks = 0; ks < 4; ++ks){
            S0 = __builtin_amdgcn_mfma_f32_16x16x32_bf16(qf[ks], kf[2*ks],   S0, 0, 0, 0);
            S1 = __builtin_amdgcn_mfma_f32_16x16x32_bf16(qf[ks], kf[2*ks+1], S1, 0, 0, 0);
        }
        // ---- vf batch issued now: latency hides under exp/Ps/lgkmcnt ----
        bf16x8 vf[8];
        #pragma unroll
        for (int ct = 0; ct < 8; ++ct)
            vf[ct] = *(const bf16x8*)(const void*)
                (Vt + vb + (size_t)(ct*16 + l16)*NN + j0 + quad*8);
        // ---- mask + exp (shift-free softmax numerator; |s| ~ O(1)) ----
        const int c0j = j0 + l16, c1j = c0j + 16;
        #pragma unroll
        for (int r = 0; r < 4; ++r){
            const float s0 = (c0j <= brow + r) ? S0[r] : -1e30f;
            const float s1 = (c1j <= brow + r) ? S1[r] : -1e30f;
            const bf16 hb0 = f2b(__expf(s0));
            const bf16 hb1 = f2b(__expf(s1));
            Ps[w][quad*4 + r][l16]      = hb0;
            Ps[w][quad*4 + r][l16 + 16] = hb1;
            l_[r] += b2f(hb0) + b2f(hb1);       // sum the rounded P
        }
        // ---- PV: A = P (A-layout via LDS), B = vf ----
        const bf16x8 pf = *(const bf16x8*)(const void*)&Ps[w][l16][quad*8];
        #pragma unroll
        for (int ct = 0; ct < 8; ++ct)
            O[ct] = __builtin_amdgcn_mfma_f32_16x16x32_bf16(pf, vf[ct], O[ct], 0, 0, 0);
    }

    // ---- reduce l across the 16 key-lanes (once), normalize -> cx ----
    {
        float inv[4];
        #pragma unroll
        for (int r = 0; r < 4; ++r){
            float rs = l_[r];
            rs += __shfl_xor(rs, 1);
            rs += __shfl_xor(rs, 2);
            rs += __shfl_xor(rs, 4);
            rs += __shfl_xor(rs, 8);
            inv[r] = 1.f/rs;
        }
        #pragma unroll
        for (int ct = 0; ct < 8; ++ct)
        #pragma unroll
        for (int r = 0; r < 4; ++r)
            Qs[wr0 + quad*4 + r][ct*16 + l16] = f2b(O[ct][r]*inv[r]);
    }
    // ---- epilogue: rows t>>2 belong to this thread's wave -> no barrier ----
    {
        const int row = t >> 2, ch0 = (t & 3)*32;
        float outv[32];
        #pragma unroll
        for (int k = 0; k < 32; ++k){
            const int ch = ch0 + k;
            float a = t_bo[ch] + skb[ch];
            #pragma unroll
            for (int f = 0; f < FIN; ++f) a += xs[row][f]*skw[f*HID + ch];
            outv[k] = a;
        }
        for (int cc = 0; cc < HID; ++cc){
            const int c = (cc + 2*row) & (HID-1);
            const float cxv = b2f(Qs[row][c]);
            #pragma unroll
            for (int k = 0; k < 32; ++k) outv[k] += cxv * t_wo[c*HID + ch0 + k];
        }
        #pragma unroll
        for (int k = 0; k < 32; ++k)
            H1[((size_t)slice*NN + q0 + row)*HID + ch0 + k] = f2b(outv[k]);
    }
}

// ---------------------------------------------------------------------------
// K3: per (b,s): load h1[m] (all 8 m), LN2, node attention (q for m=7 only),
// LN3, MLP -> node feature [128] fp32.
// ---------------------------------------------------------------------------
__global__ void k_mix(const bf16* __restrict__ H1,
                      const float* __restrict__ ln2g, const float* __restrict__ ln2b,
                      const float* __restrict__ s_wq, const float* __restrict__ s_bq,
                      const float* __restrict__ s_wk, const float* __restrict__ s_bk,
                      const float* __restrict__ s_wv, const float* __restrict__ s_bv,
                      const float* __restrict__ s_wo, const float* __restrict__ s_bo,
                      const float* __restrict__ ln3g, const float* __restrict__ ln3b,
                      const float* __restrict__ w1, const float* __restrict__ bm1,
                      const float* __restrict__ w2, const float* __restrict__ bm2,
                      float* __restrict__ Hn)
{
    const int blk = blockIdx.x;          // b*NN + s
    const int b = blk >> 11, s = blk & (NN-1);
    const int h = threadIdx.x;           // 0..127
    __shared__ float h1[TT][HID], z2[TT][HID], k2[TT][HID], v2[TT][HID];
    __shared__ float qv[HID], z3s[HID], hls[2*HID];
    __shared__ float scr[TT];
    __shared__ float rb1[HID], rb2[HID];

    #pragma unroll
    for (int m = 0; m < TT; ++m)
        h1[m][h] = b2f(H1[((size_t)(b*TT + m)*NN + s)*HID + h]);
    __syncthreads();

    const float g2v = ln2g[h], b2v = ln2b[h];
    for (int m = 0; m < TT; ++m){
        const float v = h1[m][h];
        rb1[h] = v; rb2[h] = v*v; __syncthreads();
        for (int st = 64; st > 0; st >>= 1){
            if (h < st){ rb1[h] += rb1[h+st]; rb2[h] += rb2[h+st]; }
            __syncthreads();
        }
        const float mu = rb1[0]*(1.f/HID);
        const float var = rb2[0]*(1.f/HID) - mu*mu;
        const float inv = rsqrtf(var + 1e-5f);
        __syncthreads();
        z2[m][h] = (v - mu)*inv*g2v + b2v;
    }
    __syncthreads();

    {
        float ack[TT], acv[TT];
        const float bkv = s_bk[h], bvv = s_bv[h];
        #pragma unroll
        for (int m = 0; m < TT; ++m){ ack[m] = bkv; acv[m] = bvv; }
        for (int c = 0; c < HID; ++c){
            const float wk = s_wk[c*HID + h];
            const float wv = s_wv[c*HID + h];
            #pragma unroll
            for (int m = 0; m < TT; ++m){ ack[m] += z2[m][c]*wk; acv[m] += z2[m][c]*wv; }
        }
        #pragma unroll
        for (int m = 0; m < TT; ++m){ k2[m][h] = ack[m]; v2[m][h] = acv[m]; }
        float aq = s_bq[h];
        for (int c = 0; c < HID; ++c) aq += z2[TT-1][c]*s_wq[c*HID + h];
        qv[h] = aq;
    }
    __syncthreads();

    if (h < TT){
        float d = 0.f;
        for (int c = 0; c < HID; ++c) d += qv[c]*k2[h][c];
        scr[h] = d * 0.08838834764831845f;
    }
    __syncthreads();
    float mx = -1e30f;
    #pragma unroll
    for (int m = 0; m < TT; ++m) mx = fmaxf(mx, scr[m]);
    float p[TT], se = 0.f;
    #pragma unroll
    for (int m = 0; m < TT; ++m){ p[m] = __expf(scr[m]-mx); se += p[m]; }
    const float isum = 1.f/se;
    float c2 = 0.f;
    #pragma unroll
    for (int m = 0; m < TT; ++m) c2 += p[m]*v2[m][h];
    c2 *= isum;
    __syncthreads();
    qv[h] = c2;
    __syncthreads();

    float o = s_bo[h];
    for (int c = 0; c < HID; ++c) o += qv[c]*s_wo[c*HID + h];
    const float h2 = h1[TT-1][h] + o;

    rb1[h] = h2; rb2[h] = h2*h2; __syncthreads();
    for (int st = 64; st > 0; st >>= 1){
        if (h < st){ rb1[h] += rb1[h+st]; rb2[h] += rb2[h+st]; }
        __syncthreads();
    }
    {
        const float mu = rb1[0]*(1.f/HID);
        const float var = rb2[0]*(1.f/HID) - mu*mu;
        const float inv = rsqrtf(var + 1e-5f);
        __syncthreads();
        z3s[h] = (h2 - mu)*inv*ln3g[h] + ln3b[h];
    }
    __syncthreads();

    float hid0 = bm1[h], hid1 = bm1[h+HID];
    for (int c = 0; c < HID; ++c){
        const float z = z3s[c];
        hid0 += z * w1[c*2*HID + h];
        hid1 += z * w1[c*2*HID + h + HID];
    }
    hls[h] = fmaxf(hid0, 0.f); hls[h+HID] = fmaxf(hid1, 0.f);
    __syncthreads();
    float outv = bm2[h] + h2;
    for (int j = 0; j < 2*HID; ++j) outv += hls[j]*w2[j*HID + h];
    Hn[(size_t)(b*NN + s)*HID + h] = outv;
}

// ---------------------------------------------------------------------------
// GAT
// ---------------------------------------------------------------------------
__device__ __forceinline__ void edge_decode(const int* __restrict__ ei, int e,
                                            int& src, int& dst, bool& dropped)
{
    if (e < NEDGEB){
        const int bb = e >> 15, k = e & (NEDGE-1);
        const int s0 = ei[k], d0 = ei[NEDGE + k];
        src = s0 + bb*NN; dst = d0 + bb*NN;
        dropped = (s0 == d0);     // PyG removes pre-existing self loops
    } else { src = dst = e - NEDGEB; dropped = false; }
}

__global__ void k_gat1_lin(const float* __restrict__ Hn, const float* __restrict__ W,
                           const float* __restrict__ asrc, const float* __restrict__ adst,
                           bf16* __restrict__ hw, float* __restrict__ als, float* __restrict__ ald)
{
    const int nid = blockIdx.x, c = threadIdx.x;   // 128
    __shared__ float hr[HID], r1[HID], r2[HID];
    hr[c] = Hn[(size_t)nid*HID + c];
    __syncthreads();
    float a = 0.f;
    for (int k = 0; k < HID; ++k) a += hr[k]*W[k*HID + c];
    hw[(size_t)nid*HID + c] = f2b(a);
    r1[c] = a*asrc[c]; r2[c] = a*adst[c];
    __syncthreads();
    for (int st = 16; st > 0; st >>= 1){
        if ((c & 31) < st){ r1[c] += r1[c+st]; r2[c] += r2[c+st]; }
        __syncthreads();
    }
    if ((c & 31) == 0){
        als[nid*NHEADS + (c>>5)] = r1[c];
        ald[nid*NHEADS + (c>>5)] = r2[c];
    }
}

__global__ void k_gat_edge1(const int* __restrict__ ei, const float* __restrict__ als,
                            const float* __restrict__ ald, bf16* __restrict__ ex,
                            float* __restrict__ denom)
{
    const int idx = blockIdx.x*blockDim.x + threadIdx.x;
    if (idx >= NETOT*NHEADS) return;
    const int e = idx >> 2, hd = idx & 3;
    int src, dst; bool drop;
    edge_decode(ei, e, src, dst, drop);
    if (drop){ ex[idx] = f2b(0.f); return; }
    float a = als[src*NHEADS + hd] + ald[dst*NHEADS + hd];
    a = a > 0.f ? a : 0.2f*a;
    const bf16 vb = f2b(__expf(a));
    ex[idx] = vb;
    atomicAdd(&denom[dst*NHEADS + hd], b2f(vb));
}

__global__ void k_gat_agg1(const int* __restrict__ ei, const bf16* __restrict__ ex,
                           const float* __restrict__ denom, const bf16* __restrict__ hw,
                           float* __restrict__ agg)
{
    const int t = blockIdx.x*blockDim.x + threadIdx.x;   // NETOT*128
    const int e = t >> 7, c = t & 127;
    if (e >= NETOT) return;
    const float x = b2f(ex[e*NHEADS + (c>>5)]);
    if (x == 0.f) return;
    int src, dst; bool drop;
    edge_decode(ei, e, src, dst, drop);
    const float w = x / denom[dst*NHEADS + (c>>5)];
    atomicAdd(&agg[(size_t)dst*HID + c], w * b2f(hw[(size_t)src*HID + c]));
}

__global__ void k_gat1_fin(const float* __restrict__ agg, const float* __restrict__ bias,
                           bf16* __restrict__ g1)
{
    const int t = blockIdx.x*blockDim.x + threadIdx.x;
    if (t >= NNODE*HID) return;
    const float v = agg[t] + bias[t & 127];
    g1[t] = f2b(v > 0.f ? v : expm1f(v));    // elu
}

__global__ void k_gat2_lin(const bf16* __restrict__ g1, const float* __restrict__ W,
                           const float* __restrict__ asrc, const float* __restrict__ adst,
                           bf16* __restrict__ hw2, float* __restrict__ al2s, float* __restrict__ al2d)
{
    const int nid = blockIdx.x, c = threadIdx.x;    // 64 threads = 1 wave
    __shared__ float hr[HID];
    hr[c] = b2f(g1[(size_t)nid*HID + c]);
    hr[c+64] = b2f(g1[(size_t)nid*HID + c + 64]);
    __syncthreads();
    float a = 0.f;
    for (int k = 0; k < HID; ++k) a += hr[k]*W[k*OUTCH + c];
    hw2[(size_t)nid*OUTCH + c] = f2b(a);
    float s1 = a*asrc[c], s2 = a*adst[c];
    #pragma unroll
    for (int off = 32; off > 0; off >>= 1){
        s1 += __shfl_down(s1, off);
        s2 += __shfl_down(s2, off);
    }
    if (c == 0){ al2s[nid] = s1; al2d[nid] = s2; }
}

__global__ void k_gat_edge2(const int* __restrict__ ei, const float* __restrict__ als,
                            const float* __restrict__ ald, bf16* __restrict__ ex,
                            float* __restrict__ denom)
{
    const int e = blockIdx.x*blockDim.x + threadIdx.x;
    if (e >= NETOT) return;
    int src, dst; bool drop;
    edge_decode(ei, e, src, dst, drop);
    if (drop){ ex[e] = f2b(0.f); return; }
    float a = als[src] + ald[dst];
    a = a > 0.f ? a : 0.2f*a;
    const bf16 vb = f2b(__expf(a));
    ex[e] = vb;
    atomicAdd(&denom[dst], b2f(vb));
}

__global__ void k_gat_agg2(const int* __restrict__ ei, const bf16* __restrict__ ex,
                           const float* __restrict__ denom, const bf16* __restrict__ hw2,
                           float* __restrict__ agg)
{
    const int t = blockIdx.x*blockDim.x + threadIdx.x;   // NETOT*64
    const int e = t >> 6, c = t & 63;
    if (e >= NETOT) return;
    const float x = b2f(ex[e]);
    if (x == 0.f) return;
    int src, dst; bool drop;
    edge_decode(ei, e, src, dst, drop);
    const float w = x / denom[dst];
    atomicAdd(&agg[(size_t)dst*OUTCH + c], w * b2f(hw2[(size_t)src*OUTCH + c]));
}

__global__ void k_final(const float* __restrict__ agg2, const float* __restrict__ g2b,
                        const float* __restrict__ fw, const float* __restrict__ fb,
                        float* __restrict__ out)
{
    const int nid = blockIdx.x, c = threadIdx.x;    // 64
    __shared__ float g[OUTCH];
    g[c] = agg2[(size_t)nid*OUTCH + c] + g2b[c];
    __syncthreads();
    if (c < OUTF){
        float o = fb[c];
        for (int k = 0; k < OUTCH; ++k) o += g[k]*fw[k*OUTF + c];
        const int b = nid >> 11, n = nid & (NN-1);
        out[((size_t)b*OUTF + c)*NN + n] = o;
    }
}

// ---------------------------------------------------------------------------
extern "C" void kernel_launch(void* const* d_in, const int* in_sizes, int n_in,
                              void* d_out, int out_size, void* d_ws, size_t ws_size,
                              hipStream_t stream)
{
    const float* x    = (const float*)d_in[0];
    const int*  ei    = (const int*)d_in[1];
    const float* ln1g = (const float*)d_in[2];  const float* ln1b = (const float*)d_in[3];
    const float* t_wq = (const float*)d_in[4];  const float* t_bq = (const float*)d_in[5];
    const float* t_wk = (const float*)d_in[6];  const float* t_bk = (const float*)d_in[7];
    const float* t_wv = (const float*)d_in[8];  const float* t_bv = (const float*)d_in[9];
    const float* t_wo = (const float*)d_in[10]; const float* t_bo = (const float*)d_in[11];
    const float* skw  = (const float*)d_in[12]; const float* skb  = (const float*)d_in[13];
    const float* ln2g = (const float*)d_in[14]; const float* ln2b = (const float*)d_in[15];
    const float* s_wq = (const float*)d_in[16]; const float* s_bq = (const float*)d_in[17];
    const float* s_wk = (const float*)d_in[18]; const float* s_bk = (const float*)d_in[19];
    const float* s_wv = (const float*)d_in[20]; const float* s_bv = (const float*)d_in[21];
    const float* s_wo = (const float*)d_in[22]; const float* s_bo = (const float*)d_in[23];
    const float* ln3g = (const float*)d_in[24]; const float* ln3b = (const float*)d_in[25];
    const float* w1   = (const float*)d_in[26]; const float* b1   = (const float*)d_in[27];
    const float* w2   = (const float*)d_in[28]; const float* b2   = (const float*)d_in[29];
    const float* g1w  = (const float*)d_in[30];
    const float* g1as = (const float*)d_in[31]; const float* g1ad = (const float*)d_in[32];
    const float* g1b  = (const float*)d_in[33];
    const float* g2w  = (const float*)d_in[34];
    const float* g2as = (const float*)d_in[35]; const float* g2ad = (const float*)d_in[36];
    const float* g2b  = (const float*)d_in[37];
    const float* ffw  = (const float*)d_in[38]; const float* ffb  = (const float*)d_in[39];
    float* out = (float*)d_out;

    const size_t MiB = 1024u*1024u;
    const bool wide = ws_size >= 52*MiB;   // K(16)+Vt(16)+H1(16)+Hn(4)

    char* base = (char*)d_ws;
    bf16 *Kb, *Vtb, *H1;
    float* Hn;
    char* gat_base;
    if (wide){
        Kb  = (bf16*)(base + 0*MiB);       // 16 MiB (all 32 slices, row-major)
        Vtb = (bf16*)(base + 16*MiB);      // 16 MiB ([slice][ch][key])
        H1  = (bf16*)(base + 32*MiB);      // 16 MiB
        Hn  = (float*)(base + 48*MiB);     // 4 MiB
        gat_base = base;                   // aliases Kb/Vtb (dead after attn)
    } else {
        H1  = (bf16*)(base + 0*MiB);       // 16 MiB
        Hn  = (float*)(base + 16*MiB);     // 4 MiB
        Kb  = (bf16*)(base + 20*MiB);      // 0.5 MiB (one slice)
        Vtb = (bf16*)(base + 20*MiB + 512u*1024u);
        gat_base = base;                   // aliases H1 (dead after k_mix)
    }
    // GAT scratch (~12.9 MiB) inside gat_base
    char* w = gat_base;
    auto alloc = [&](size_t bytes){ void* p = (void*)w; w += (bytes + 255) & ~(size_t)255; return p; };
    bf16*  hw1  = (bf16*) alloc((size_t)NNODE*HID*sizeof(bf16));
    float* als1 = (float*)alloc((size_t)NNODE*NHEADS*sizeof(float));
    float* ald1 = (float*)alloc((size_t)NNODE*NHEADS*sizeof(float));
    bf16*  ex1  = (bf16*) alloc((size_t)NETOT*NHEADS*sizeof(bf16));
    float* den1 = (float*)alloc((size_t)NNODE*NHEADS*sizeof(float));
    float* agg1 = (float*)alloc((size_t)NNODE*HID*sizeof(float));
    bf16*  g1o  = (bf16*) alloc((size_t)NNODE*HID*sizeof(bf16));
    bf16*  hw2  = (bf16*) alloc((size_t)NNODE*OUTCH*sizeof(bf16));
    float* als2 = (float*)alloc((size_t)NNODE*sizeof(float));
    float* ald2 = (float*)alloc((size_t)NNODE*sizeof(float));
    bf16*  ex2  = (bf16*) alloc((size_t)NETOT*sizeof(bf16));
    float* den2 = (float*)alloc((size_t)NNODE*sizeof(float));
    float* agg2 = (float*)alloc((size_t)NNODE*OUTCH*sizeof(float));

    // ---- trunk ----
    if (wide){
        k_kv<<<PROWS, HID, 0, stream>>>(x, ln1g, ln1b, t_wk, t_bk, t_wv, t_bv, 0, Kb, Vtb);
        // grid: x = slice (XCD-stable), y = tile rank (0 = biggest, LPT)
        k_attn_mfma<<<dim3(BM, NTILE), 256, 0, stream>>>(x, Kb, Vtb, ln1g, ln1b, t_wq, t_bq,
                                                         skw, skb, t_wo, t_bo, 0, H1);
    } else {
        for (int s = 0; s < BM; ++s){
            k_kv<<<NN, HID, 0, stream>>>(x, ln1g, ln1b, t_wk, t_bk, t_wv, t_bv, s*NN, Kb, Vtb);
            k_attn_mfma<<<dim3(1, NTILE), 256, 0, stream>>>(x, Kb, Vtb, ln1g, ln1b, t_wq, t_bq,
                                                            skw, skb, t_wo, t_bo, s, H1);
        }
    }
    k_mix<<<BB*NN, HID, 0, stream>>>(H1, ln2g, ln2b, s_wq, s_bq, s_wk, s_bk,
                                     s_wv, s_bv, s_wo, s_bo, ln3g, ln3b,
                                     w1, b1, w2, b2, Hn);

    // ---- GAT (accumulators zeroed after k_mix; region was dead/poisoned) ----
    hipMemsetAsync(den1, 0, (size_t)NNODE*NHEADS*sizeof(float), stream);
    hipMemsetAsync(agg1, 0, (size_t)NNODE*HID*sizeof(float), stream);
    hipMemsetAsync(den2, 0, (size_t)NNODE*sizeof(float), stream);
    hipMemsetAsync(agg2, 0, (size_t)NNODE*OUTCH*sizeof(float), stream);

    k_gat1_lin<<<NNODE, HID, 0, stream>>>(Hn, g1w, g1as, g1ad, hw1, als1, ald1);
    k_gat_edge1<<<(NETOT*NHEADS + 255)/256, 256, 0, stream>>>(ei, als1, ald1, ex1, den1);
    k_gat_agg1<<<(NETOT*HID)/256, 256, 0, stream>>>(ei, ex1, den1, hw1, agg1);
    k_gat1_fin<<<(NNODE*HID)/256, 256, 0, stream>>>(agg1, g1b, g1o);
    k_gat2_lin<<<NNODE, OUTCH, 0, stream>>>(g1o, g2w, g2as, g2ad, hw2, als2, ald2);
    k_gat_edge2<<<(NETOT + 255)/256, 256, 0, stream>>>(ei, als2, ald2, ex2, den2);
    k_gat_agg2<<<(NETOT*OUTCH)/256, 256, 0, stream>>>(ei, ex2, den2, hw2, agg2);
    k_final<<<NNODE, OUTCH, 0, stream>>>(agg2, g2b, ffw, ffb, out);
}

// Round 13
// 1212.910 us; speedup vs baseline: 1.3109x; 1.0909x over previous
//
#include <hip/hip_runtime.h>
#include <hip/hip_bf16.h>
#include <stdint.h>

// ---------------------------------------------------------------------------
// PFGAT: [B,T,N,F]=[4,8,2048,16] transformer (causal attn over N per (b,t),
// node attn over T-slots, MLP at last slot) -> 2x GATConv -> FFN -> [B,14,N].
// fp32 I/O, fp32 compute, bf16 intermediate storage.
// R13: MFMA flash attn with cooperative LDS staging: K/V tiles loaded once
// per block (coalesced b128, ~32 txns/step vs 256 scattered + 4x wave dedup),
// frags from padded LDS. Vt stored key-tiled [slice][kt][ch][32] for slab
// contiguity. Block-uniform loop bound (barrier-safe); XCD swizzle kept.
// ---------------------------------------------------------------------------

#define BB     4
#define TT     8
#define NN     2048
#define FIN    16
#define HID    128
#define BM     (BB*TT)            // 32 attention slices
#define PROWS  (BM*NN)            // 65536 rows
#define NHEADS 4
#define OUTCH  64
#define OUTF   14
#define NEDGE  32768
#define NEDGEB (NEDGE*BB)         // 131072
#define NNODE  (BB*NN)            // 8192
#define NETOT  (NEDGEB + NNODE)   // 139264 (edges + self loops)

#define TQ     64                 // query tile (rows per block)
#define NTILE  (NN/TQ)            // 32 query tiles per slice

typedef __hip_bfloat16 bf16;
typedef __attribute__((ext_vector_type(8))) short bf16x8;   // MFMA A/B frag
typedef __attribute__((ext_vector_type(4))) float f32x4;    // MFMA C/D frag

__device__ __forceinline__ float b2f(bf16 v){ return __bfloat162float(v); }
__device__ __forceinline__ bf16  f2b(float f){ return __float2bfloat16(f); }

// ---------------------------------------------------------------------------
// K1: per row: LN1 over F=16 -> k,v projections; K row-major, V key-tiled
// (Vt[slice][key>>5][ch][key&31]) so each 32-key slab is 8KB contiguous.
// ---------------------------------------------------------------------------
__global__ void k_kv(const float* __restrict__ x,
                     const float* __restrict__ g1, const float* __restrict__ bb1,
                     const float* __restrict__ wk, const float* __restrict__ bk,
                     const float* __restrict__ wv, const float* __restrict__ bv,
                     int in_off, bf16* __restrict__ K, bf16* __restrict__ Vt)
{
    const int rloc = blockIdx.x;
    const int rin  = rloc + in_off;
    const int h = threadIdx.x;       // 0..127
    __shared__ float xr[FIN], lnv[FIN];
    if (h < FIN) xr[h] = x[(size_t)rin*FIN + h];
    __syncthreads();
    float mu = 0.f;
    #pragma unroll
    for (int f = 0; f < FIN; ++f) mu += xr[f];
    mu *= (1.f/FIN);
    float var = 0.f;
    #pragma unroll
    for (int f = 0; f < FIN; ++f){ float d = xr[f]-mu; var += d*d; }
    var *= (1.f/FIN);
    const float inv = rsqrtf(var + 1e-5f);
    if (h < FIN) lnv[h] = (xr[h]-mu)*inv*g1[h] + bb1[h];
    __syncthreads();
    float ak = bk[h], av = bv[h];
    #pragma unroll
    for (int f = 0; f < FIN; ++f){
        const float l = lnv[f];
        ak += l * wk[f*HID + h];
        av += l * wv[f*HID + h];
    }
    K[(size_t)rloc*HID + h] = f2b(ak);
    const int slice = rloc >> 11;            // 0 in narrow mode
    const int key   = rloc & (NN-1);
    Vt[(((size_t)slice*(NN/32) + (key>>5))*HID + h)*32 + (key&31)] = f2b(av);
}

// ---------------------------------------------------------------------------
// K2 (MFMA flash, staged): blockIdx.x = slice (XCD-stable), blockIdx.y =
// tile rank (0 = biggest, LPT). Per 32-key step: 256 threads cooperatively
// stage K slab (32x128) + V slab (128x32) -> LDS (coalesced b128), barrier,
// frags via padded ds_read_b128, S = Q.K^T (8 MFMAs), mask+exp (no-max
// softmax, scores O(1)), P via per-wave LDS roundtrip, PV (8 MFMAs), barrier.
// Block-uniform trip count (waves past their causal bound skip compute only).
// ---------------------------------------------------------------------------
__global__ __launch_bounds__(256)
void k_attn_mfma(const float* __restrict__ x,
                 const bf16* __restrict__ K, const bf16* __restrict__ Vt,
                 const float* __restrict__ g1, const float* __restrict__ bb1,
                 const float* __restrict__ wq, const float* __restrict__ bq,
                 const float* __restrict__ skw, const float* __restrict__ skb,
                 const float* __restrict__ t_wo, const float* __restrict__ t_bo,
                 int slice_off, bf16* __restrict__ H1)
{
    const int tile  = (NTILE-1) - (int)blockIdx.y;   // big tiles first
    const int q0    = tile*TQ;
    const int slice = blockIdx.x + slice_off;
    const int t     = threadIdx.x;
    const int w     = t >> 6;            // wave 0..3
    const int lane  = t & 63;
    const int quad  = lane >> 4;
    const int l16   = lane & 15;
    const int wr0   = w*16;              // wave's first local row

    __shared__ float xs [TQ][FIN];                 // raw x rows (skip)
    __shared__ float lns[TQ][FIN];                 // LN1(x) rows
    __shared__ bf16  Qs [TQ][136];                 // Q (scaled) bf16; cx later
    __shared__ bf16  Ps [4][16][40];               // per-wave P roundtrip
    __shared__ bf16  Ks [32*136];                  // staged K tile (pad 8)
    __shared__ bf16  Vs [128*40];                  // staged V tile (pad 8)

    // ---- stage x rows ----
    for (int u = t; u < TQ*FIN; u += 256)
        ((float*)xs)[u] = x[((size_t)slice*NN + q0)*FIN + u];
    __syncthreads();
    // ---- LN1 per row ----
    if (t < TQ){
        float mu = 0.f;
        #pragma unroll
        for (int f = 0; f < FIN; ++f) mu += xs[t][f];
        mu *= (1.f/FIN);
        float var = 0.f;
        #pragma unroll
        for (int f = 0; f < FIN; ++f){ float d = xs[t][f]-mu; var += d*d; }
        var *= (1.f/FIN);
        const float inv = rsqrtf(var + 1e-5f);
        #pragma unroll
        for (int f = 0; f < FIN; ++f)
            lns[t][f] = (xs[t][f]-mu)*inv*g1[f] + bb1[f];
    }
    __syncthreads();
    // ---- Q (scale folded) -> Qs bf16 ----
    {
        const int r = t >> 2, c0 = (t & 3)*32;
        const float scale = 0.08838834764831845f;   // 1/sqrt(128)
        #pragma unroll
        for (int k = 0; k < 32; ++k){
            const int ch = c0 + k;
            float a = bq[ch];
            #pragma unroll
            for (int f = 0; f < FIN; ++f) a += lns[r][f]*wq[f*HID + ch];
            Qs[r][ch] = f2b(a*scale);
        }
    }
    __syncthreads();

    // ---- Q A-frags: A[m=l16][k=quad*8+j], k-step ks*32 ----
    bf16x8 qf[4];
    #pragma unroll
    for (int ks = 0; ks < 4; ++ks)
        qf[ks] = *(const bf16x8*)(const void*)&Qs[wr0 + l16][ks*32 + quad*8];

    f32x4 O[8];
    #pragma unroll
    for (int ct = 0; ct < 8; ++ct) O[ct] = (f32x4){0.f,0.f,0.f,0.f};
    float l_[4] = {0.f,0.f,0.f,0.f};     // per-lane partial row sums

    const size_t kb = (size_t)blockIdx.x * NN * HID;                 // K slice
    const size_t vb = (size_t)blockIdx.x * (size_t)(NN/32) * HID*32; // Vt slice
    const int jend_blk = q0 + TQ - 1;       // block-uniform loop bound
    const int my_jmax  = q0 + wr0 + 15;     // wave-uniform causal bound
    const int brow = q0 + wr0 + quad*4;     // +reg = my global q-row

    for (int j0 = 0; j0 <= jend_blk; j0 += 32){
        // ---- cooperative staging: K slab + V slab, coalesced b128 ----
        {
            const bf16* ksl = K  + kb + (size_t)j0*HID;           // 32x128
            const bf16* vsl = Vt + vb + (size_t)(j0>>5)*(HID*32); // 128x32
            #pragma unroll
            for (int it = 0; it < 2; ++it){
                const int c = t + it*256;          // 512 chunks of 8 bf16
                *(bf16x8*)(void*)&Ks[(c>>4)*136 + (c&15)*8] =
                    *(const bf16x8*)(const void*)(ksl + c*8);
                *(bf16x8*)(void*)&Vs[(c>>2)*40 + (c&3)*8] =
                    *(const bf16x8*)(const void*)(vsl + c*8);
            }
        }
        __syncthreads();

        if (j0 <= my_jmax){              // wave-uniform compute guard
            // ---- S tiles: cols j0..j0+15 (S0) and j0+16..j0+31 (S1) ----
            f32x4 S0 = (f32x4){0.f,0.f,0.f,0.f}, S1 = S0;
            #pragma unroll
            for (int ks = 0; ks < 4; ++ks){
                const bf16x8 kf0 = *(const bf16x8*)(const void*)
                    &Ks[(l16     )*136 + ks*32 + quad*8];
                const bf16x8 kf1 = *(const bf16x8*)(const void*)
                    &Ks[(l16 + 16)*136 + ks*32 + quad*8];
                S0 = __builtin_amdgcn_mfma_f32_16x16x32_bf16(qf[ks], kf0, S0, 0, 0, 0);
                S1 = __builtin_amdgcn_mfma_f32_16x16x32_bf16(qf[ks], kf1, S1, 0, 0, 0);
            }
            // ---- mask + exp ----
            const int c0j = j0 + l16, c1j = c0j + 16;
            #pragma unroll
            for (int r = 0; r < 4; ++r){
                const float s0 = (c0j <= brow + r) ? S0[r] : -1e30f;
                const float s1 = (c1j <= brow + r) ? S1[r] : -1e30f;
                const bf16 hb0 = f2b(__expf(s0));
                const bf16 hb1 = f2b(__expf(s1));
                Ps[w][quad*4 + r][l16]      = hb0;
                Ps[w][quad*4 + r][l16 + 16] = hb1;
                l_[r] += b2f(hb0) + b2f(hb1);       // sum the rounded P
            }
            // ---- PV: A = P (A-layout via LDS), B = Vs frags ----
            const bf16x8 pf = *(const bf16x8*)(const void*)&Ps[w][l16][quad*8];
            #pragma unroll
            for (int ct = 0; ct < 8; ++ct){
                const bf16x8 vf = *(const bf16x8*)(const void*)
                    &Vs[(ct*16 + l16)*40 + quad*8];
                O[ct] = __builtin_amdgcn_mfma_f32_16x16x32_bf16(pf, vf, O[ct], 0, 0, 0);
            }
        }
        __syncthreads();
    }

    // ---- reduce l across the 16 key-lanes (once), normalize -> cx ----
    {
        float inv[4];
        #pragma unroll
        for (int r = 0; r < 4; ++r){
            float rs = l_[r];
            rs += __shfl_xor(rs, 1);
            rs += __shfl_xor(rs, 2);
            rs += __shfl_xor(rs, 4);
            rs += __shfl_xor(rs, 8);
            inv[r] = 1.f/rs;
        }
        #pragma unroll
        for (int ct = 0; ct < 8; ++ct)
        #pragma unroll
        for (int r = 0; r < 4; ++r)
            Qs[wr0 + quad*4 + r][ct*16 + l16] = f2b(O[ct][r]*inv[r]);
    }
    // ---- epilogue: rows t>>2 belong to this thread's wave -> no barrier ----
    {
        const int row = t >> 2, ch0 = (t & 3)*32;
        float outv[32];
        #pragma unroll
        for (int k = 0; k < 32; ++k){
            const int ch = ch0 + k;
            float a = t_bo[ch] + skb[ch];
            #pragma unroll
            for (int f = 0; f < FIN; ++f) a += xs[row][f]*skw[f*HID + ch];
            outv[k] = a;
        }
        for (int cc = 0; cc < HID; ++cc){
            const int c = (cc + 2*row) & (HID-1);
            const float cxv = b2f(Qs[row][c]);
            #pragma unroll
            for (int k = 0; k < 32; ++k) outv[k] += cxv * t_wo[c*HID + ch0 + k];
        }
        #pragma unroll
        for (int k = 0; k < 32; ++k)
            H1[((size_t)slice*NN + q0 + row)*HID + ch0 + k] = f2b(outv[k]);
    }
}

// ---------------------------------------------------------------------------
// K3: per (b,s): load h1[m] (all 8 m), LN2, node attention (q for m=7 only),
// LN3, MLP -> node feature [128] fp32.
// ---------------------------------------------------------------------------
__global__ void k_mix(const bf16* __restrict__ H1,
                      const float* __restrict__ ln2g, const float* __restrict__ ln2b,
                      const float* __restrict__ s_wq, const float* __restrict__ s_bq,
                      const float* __restrict__ s_wk, const float* __restrict__ s_bk,
                      const float* __restrict__ s_wv, const float* __restrict__ s_bv,
                      const float* __restrict__ s_wo, const float* __restrict__ s_bo,
                      const float* __restrict__ ln3g, const float* __restrict__ ln3b,
                      const float* __restrict__ w1, const float* __restrict__ bm1,
                      const float* __restrict__ w2, const float* __restrict__ bm2,
                      float* __restrict__ Hn)
{
    const int blk = blockIdx.x;          // b*NN + s
    const int b = blk >> 11, s = blk & (NN-1);
    const int h = threadIdx.x;           // 0..127
    __shared__ float h1[TT][HID], z2[TT][HID], k2[TT][HID], v2[TT][HID];
    __shared__ float qv[HID], z3s[HID], hls[2*HID];
    __shared__ float scr[TT];
    __shared__ float rb1[HID], rb2[HID];

    #pragma unroll
    for (int m = 0; m < TT; ++m)
        h1[m][h] = b2f(H1[((size_t)(b*TT + m)*NN + s)*HID + h]);
    __syncthreads();

    const float g2v = ln2g[h], b2v = ln2b[h];
    for (int m = 0; m < TT; ++m){
        const float v = h1[m][h];
        rb1[h] = v; rb2[h] = v*v; __syncthreads();
        for (int st = 64; st > 0; st >>= 1){
            if (h < st){ rb1[h] += rb1[h+st]; rb2[h] += rb2[h+st]; }
            __syncthreads();
        }
        const float mu = rb1[0]*(1.f/HID);
        const float var = rb2[0]*(1.f/HID) - mu*mu;
        const float inv = rsqrtf(var + 1e-5f);
        __syncthreads();
        z2[m][h] = (v - mu)*inv*g2v + b2v;
    }
    __syncthreads();

    {
        float ack[TT], acv[TT];
        const float bkv = s_bk[h], bvv = s_bv[h];
        #pragma unroll
        for (int m = 0; m < TT; ++m){ ack[m] = bkv; acv[m] = bvv; }
        for (int c = 0; c < HID; ++c){
            const float wk = s_wk[c*HID + h];
            const float wv = s_wv[c*HID + h];
            #pragma unroll
            for (int m = 0; m < TT; ++m){ ack[m] += z2[m][c]*wk; acv[m] += z2[m][c]*wv; }
        }
        #pragma unroll
        for (int m = 0; m < TT; ++m){ k2[m][h] = ack[m]; v2[m][h] = acv[m]; }
        float aq = s_bq[h];
        for (int c = 0; c < HID; ++c) aq += z2[TT-1][c]*s_wq[c*HID + h];
        qv[h] = aq;
    }
    __syncthreads();

    if (h < TT){
        float d = 0.f;
        for (int c = 0; c < HID; ++c) d += qv[c]*k2[h][c];
        scr[h] = d * 0.08838834764831845f;
    }
    __syncthreads();
    float mx = -1e30f;
    #pragma unroll
    for (int m = 0; m < TT; ++m) mx = fmaxf(mx, scr[m]);
    float p[TT], se = 0.f;
    #pragma unroll
    for (int m = 0; m < TT; ++m){ p[m] = __expf(scr[m]-mx); se += p[m]; }
    const float isum = 1.f/se;
    float c2 = 0.f;
    #pragma unroll
    for (int m = 0; m < TT; ++m) c2 += p[m]*v2[m][h];
    c2 *= isum;
    __syncthreads();
    qv[h] = c2;
    __syncthreads();

    float o = s_bo[h];
    for (int c = 0; c < HID; ++c) o += qv[c]*s_wo[c*HID + h];
    const float h2 = h1[TT-1][h] + o;

    rb1[h] = h2; rb2[h] = h2*h2; __syncthreads();
    for (int st = 64; st > 0; st >>= 1){
        if (h < st){ rb1[h] += rb1[h+st]; rb2[h] += rb2[h+st]; }
        __syncthreads();
    }
    {
        const float mu = rb1[0]*(1.f/HID);
        const float var = rb2[0]*(1.f/HID) - mu*mu;
        const float inv = rsqrtf(var + 1e-5f);
        __syncthreads();
        z3s[h] = (h2 - mu)*inv*ln3g[h] + ln3b[h];
    }
    __syncthreads();

    float hid0 = bm1[h], hid1 = bm1[h+HID];
    for (int c = 0; c < HID; ++c){
        const float z = z3s[c];
        hid0 += z * w1[c*2*HID + h];
        hid1 += z * w1[c*2*HID + h + HID];
    }
    hls[h] = fmaxf(hid0, 0.f); hls[h+HID] = fmaxf(hid1, 0.f);
    __syncthreads();
    float outv = bm2[h] + h2;
    for (int j = 0; j < 2*HID; ++j) outv += hls[j]*w2[j*HID + h];
    Hn[(size_t)(b*NN + s)*HID + h] = outv;
}

// ---------------------------------------------------------------------------
// GAT
// ---------------------------------------------------------------------------
__device__ __forceinline__ void edge_decode(const int* __restrict__ ei, int e,
                                            int& src, int& dst, bool& dropped)
{
    if (e < NEDGEB){
        const int bb = e >> 15, k = e & (NEDGE-1);
        const int s0 = ei[k], d0 = ei[NEDGE + k];
        src = s0 + bb*NN; dst = d0 + bb*NN;
        dropped = (s0 == d0);     // PyG removes pre-existing self loops
    } else { src = dst = e - NEDGEB; dropped = false; }
}

__global__ void k_gat1_lin(const float* __restrict__ Hn, const float* __restrict__ W,
                           const float* __restrict__ asrc, const float* __restrict__ adst,
                           bf16* __restrict__ hw, float* __restrict__ als, float* __restrict__ ald)
{
    const int nid = blockIdx.x, c = threadIdx.x;   // 128
    __shared__ float hr[HID], r1[HID], r2[HID];
    hr[c] = Hn[(size_t)nid*HID + c];
    __syncthreads();
    float a = 0.f;
    for (int k = 0; k < HID; ++k) a += hr[k]*W[k*HID + c];
    hw[(size_t)nid*HID + c] = f2b(a);
    r1[c] = a*asrc[c]; r2[c] = a*adst[c];
    __syncthreads();
    for (int st = 16; st > 0; st >>= 1){
        if ((c & 31) < st){ r1[c] += r1[c+st]; r2[c] += r2[c+st]; }
        __syncthreads();
    }
    if ((c & 31) == 0){
        als[nid*NHEADS + (c>>5)] = r1[c];
        ald[nid*NHEADS + (c>>5)] = r2[c];
    }
}

__global__ void k_gat_edge1(const int* __restrict__ ei, const float* __restrict__ als,
                            const float* __restrict__ ald, bf16* __restrict__ ex,
                            float* __restrict__ denom)
{
    const int idx = blockIdx.x*blockDim.x + threadIdx.x;
    if (idx >= NETOT*NHEADS) return;
    const int e = idx >> 2, hd = idx & 3;
    int src, dst; bool drop;
    edge_decode(ei, e, src, dst, drop);
    if (drop){ ex[idx] = f2b(0.f); return; }
    float a = als[src*NHEADS + hd] + ald[dst*NHEADS + hd];
    a = a > 0.f ? a : 0.2f*a;
    const bf16 vb = f2b(__expf(a));
    ex[idx] = vb;
    atomicAdd(&denom[dst*NHEADS + hd], b2f(vb));
}

__global__ void k_gat_agg1(const int* __restrict__ ei, const bf16* __restrict__ ex,
                           const float* __restrict__ denom, const bf16* __restrict__ hw,
                           float* __restrict__ agg)
{
    const int t = blockIdx.x*blockDim.x + threadIdx.x;   // NETOT*128
    const int e = t >> 7, c = t & 127;
    if (e >= NETOT) return;
    const float x = b2f(ex[e*NHEADS + (c>>5)]);
    if (x == 0.f) return;
    int src, dst; bool drop;
    edge_decode(ei, e, src, dst, drop);
    const float w = x / denom[dst*NHEADS + (c>>5)];
    atomicAdd(&agg[(size_t)dst*HID + c], w * b2f(hw[(size_t)src*HID + c]));
}

__global__ void k_gat1_fin(const float* __restrict__ agg, const float* __restrict__ bias,
                           bf16* __restrict__ g1)
{
    const int t = blockIdx.x*blockDim.x + threadIdx.x;
    if (t >= NNODE*HID) return;
    const float v = agg[t] + bias[t & 127];
    g1[t] = f2b(v > 0.f ? v : expm1f(v));    // elu
}

__global__ void k_gat2_lin(const bf16* __restrict__ g1, const float* __restrict__ W,
                           const float* __restrict__ asrc, const float* __restrict__ adst,
                           bf16* __restrict__ hw2, float* __restrict__ al2s, float* __restrict__ al2d)
{
    const int nid = blockIdx.x, c = threadIdx.x;    // 64 threads = 1 wave
    __shared__ float hr[HID];
    hr[c] = b2f(g1[(size_t)nid*HID + c]);
    hr[c+64] = b2f(g1[(size_t)nid*HID + c + 64]);
    __syncthreads();
    float a = 0.f;
    for (int k = 0; k < HID; ++k) a += hr[k]*W[k*OUTCH + c];
    hw2[(size_t)nid*OUTCH + c] = f2b(a);
    float s1 = a*asrc[c], s2 = a*adst[c];
    #pragma unroll
    for (int off = 32; off > 0; off >>= 1){
        s1 += __shfl_down(s1, off);
        s2 += __shfl_down(s2, off);
    }
    if (c == 0){ al2s[nid] = s1; al2d[nid] = s2; }
}

__global__ void k_gat_edge2(const int* __restrict__ ei, const float* __restrict__ als,
                            const float* __restrict__ ald, bf16* __restrict__ ex,
                            float* __restrict__ denom)
{
    const int e = blockIdx.x*blockDim.x + threadIdx.x;
    if (e >= NETOT) return;
    int src, dst; bool drop;
    edge_decode(ei, e, src, dst, drop);
    if (drop){ ex[e] = f2b(0.f); return; }
    float a = als[src] + ald[dst];
    a = a > 0.f ? a : 0.2f*a;
    const bf16 vb = f2b(__expf(a));
    ex[e] = vb;
    atomicAdd(&denom[dst], b2f(vb));
}

__global__ void k_gat_agg2(const int* __restrict__ ei, const bf16* __restrict__ ex,
                           const float* __restrict__ denom, const bf16* __restrict__ hw2,
                           float* __restrict__ agg)
{
    const int t = blockIdx.x*blockDim.x + threadIdx.x;   // NETOT*64
    const int e = t >> 6, c = t & 63;
    if (e >= NETOT) return;
    const float x = b2f(ex[e]);
    if (x == 0.f) return;
    int src, dst; bool drop;
    edge_decode(ei, e, src, dst, drop);
    const float w = x / denom[dst];
    atomicAdd(&agg[(size_t)dst*OUTCH + c], w * b2f(hw2[(size_t)src*OUTCH + c]));
}

__global__ void k_final(const float* __restrict__ agg2, const float* __restrict__ g2b,
                        const float* __restrict__ fw, const float* __restrict__ fb,
                        float* __restrict__ out)
{
    const int nid = blockIdx.x, c = threadIdx.x;    // 64
    __shared__ float g[OUTCH];
    g[c] = agg2[(size_t)nid*OUTCH + c] + g2b[c];
    __syncthreads();
    if (c < OUTF){
        float o = fb[c];
        for (int k = 0; k < OUTCH; ++k) o += g[k]*fw[k*OUTF + c];
        const int b = nid >> 11, n = nid & (NN-1);
        out[((size_t)b*OUTF + c)*NN + n] = o;
    }
}

// ---------------------------------------------------------------------------
extern "C" void kernel_launch(void* const* d_in, const int* in_sizes, int n_in,
                              void* d_out, int out_size, void* d_ws, size_t ws_size,
                              hipStream_t stream)
{
    const float* x    = (const float*)d_in[0];
    const int*  ei    = (const int*)d_in[1];
    const float* ln1g = (const float*)d_in[2];  const float* ln1b = (const float*)d_in[3];
    const float* t_wq = (const float*)d_in[4];  const float* t_bq = (const float*)d_in[5];
    const float* t_wk = (const float*)d_in[6];  const float* t_bk = (const float*)d_in[7];
    const float* t_wv = (const float*)d_in[8];  const float* t_bv = (const float*)d_in[9];
    const float* t_wo = (const float*)d_in[10]; const float* t_bo = (const float*)d_in[11];
    const float* skw  = (const float*)d_in[12]; const float* skb  = (const float*)d_in[13];
    const float* ln2g = (const float*)d_in[14]; const float* ln2b = (const float*)d_in[15];
    const float* s_wq = (const float*)d_in[16]; const float* s_bq = (const float*)d_in[17];
    const float* s_wk = (const float*)d_in[18]; const float* s_bk = (const float*)d_in[19];
    const float* s_wv = (const float*)d_in[20]; const float* s_bv = (const float*)d_in[21];
    const float* s_wo = (const float*)d_in[22]; const float* s_bo = (const float*)d_in[23];
    const float* ln3g = (const float*)d_in[24]; const float* ln3b = (const float*)d_in[25];
    const float* w1   = (const float*)d_in[26]; const float* b1   = (const float*)d_in[27];
    const float* w2   = (const float*)d_in[28]; const float* b2   = (const float*)d_in[29];
    const float* g1w  = (const float*)d_in[30];
    const float* g1as = (const float*)d_in[31]; const float* g1ad = (const float*)d_in[32];
    const float* g1b  = (const float*)d_in[33];
    const float* g2w  = (const float*)d_in[34];
    const float* g2as = (const float*)d_in[35]; const float* g2ad = (const float*)d_in[36];
    const float* g2b  = (const float*)d_in[37];
    const float* ffw  = (const float*)d_in[38]; const float* ffb  = (const float*)d_in[39];
    float* out = (float*)d_out;

    const size_t MiB = 1024u*1024u;
    const bool wide = ws_size >= 52*MiB;   // K(16)+Vt(16)+H1(16)+Hn(4)

    char* base = (char*)d_ws;
    bf16 *Kb, *Vtb, *H1;
    float* Hn;
    char* gat_base;
    if (wide){
        Kb  = (bf16*)(base + 0*MiB);       // 16 MiB (all 32 slices, row-major)
        Vtb = (bf16*)(base + 16*MiB);      // 16 MiB ([slice][kt][ch][32])
        H1  = (bf16*)(base + 32*MiB);      // 16 MiB
        Hn  = (float*)(base + 48*MiB);     // 4 MiB
        gat_base = base;                   // aliases Kb/Vtb (dead after attn)
    } else {
        H1  = (bf16*)(base + 0*MiB);       // 16 MiB
        Hn  = (float*)(base + 16*MiB);     // 4 MiB
        Kb  = (bf16*)(base + 20*MiB);      // 0.5 MiB (one slice)
        Vtb = (bf16*)(base + 20*MiB + 512u*1024u);
        gat_base = base;                   // aliases H1 (dead after k_mix)
    }
    // GAT scratch (~12.9 MiB) inside gat_base
    char* w = gat_base;
    auto alloc = [&](size_t bytes){ void* p = (void*)w; w += (bytes + 255) & ~(size_t)255; return p; };
    bf16*  hw1  = (bf16*) alloc((size_t)NNODE*HID*sizeof(bf16));
    float* als1 = (float*)alloc((size_t)NNODE*NHEADS*sizeof(float));
    float* ald1 = (float*)alloc((size_t)NNODE*NHEADS*sizeof(float));
    bf16*  ex1  = (bf16*) alloc((size_t)NETOT*NHEADS*sizeof(bf16));
    float* den1 = (float*)alloc((size_t)NNODE*NHEADS*sizeof(float));
    float* agg1 = (float*)alloc((size_t)NNODE*HID*sizeof(float));
    bf16*  g1o  = (bf16*) alloc((size_t)NNODE*HID*sizeof(bf16));
    bf16*  hw2  = (bf16*) alloc((size_t)NNODE*OUTCH*sizeof(bf16));
    float* als2 = (float*)alloc((size_t)NNODE*sizeof(float));
    float* ald2 = (float*)alloc((size_t)NNODE*sizeof(float));
    bf16*  ex2  = (bf16*) alloc((size_t)NETOT*sizeof(bf16));
    float* den2 = (float*)alloc((size_t)NNODE*sizeof(float));
    float* agg2 = (float*)alloc((size_t)NNODE*OUTCH*sizeof(float));

    // ---- trunk ----
    if (wide){
        k_kv<<<PROWS, HID, 0, stream>>>(x, ln1g, ln1b, t_wk, t_bk, t_wv, t_bv, 0, Kb, Vtb);
        // grid: x = slice (XCD-stable), y = tile rank (0 = biggest, LPT)
        k_attn_mfma<<<dim3(BM, NTILE), 256, 0, stream>>>(x, Kb, Vtb, ln1g, ln1b, t_wq, t_bq,
                                                         skw, skb, t_wo, t_bo, 0, H1);
    } else {
        for (int s = 0; s < BM; ++s){
            k_kv<<<NN, HID, 0, stream>>>(x, ln1g, ln1b, t_wk, t_bk, t_wv, t_bv, s*NN, Kb, Vtb);
            k_attn_mfma<<<dim3(1, NTILE), 256, 0, stream>>>(x, Kb, Vtb, ln1g, ln1b, t_wq, t_bq,
                                                            skw, skb, t_wo, t_bo, s, H1);
        }
    }
    k_mix<<<BB*NN, HID, 0, stream>>>(H1, ln2g, ln2b, s_wq, s_bq, s_wk, s_bk,
                                     s_wv, s_bv, s_wo, s_bo, ln3g, ln3b,
                                     w1, b1, w2, b2, Hn);

    // ---- GAT (accumulators zeroed after k_mix; region was dead/poisoned) ----
    hipMemsetAsync(den1, 0, (size_t)NNODE*NHEADS*sizeof(float), stream);
    hipMemsetAsync(agg1, 0, (size_t)NNODE*HID*sizeof(float), stream);
    hipMemsetAsync(den2, 0, (size_t)NNODE*sizeof(float), stream);
    hipMemsetAsync(agg2, 0, (size_t)NNODE*OUTCH*sizeof(float), stream);

    k_gat1_lin<<<NNODE, HID, 0, stream>>>(Hn, g1w, g1as, g1ad, hw1, als1, ald1);
    k_gat_edge1<<<(NETOT*NHEADS + 255)/256, 256, 0, stream>>>(ei, als1, ald1, ex1, den1);
    k_gat_agg1<<<(NETOT*HID)/256, 256, 0, stream>>>(ei, ex1, den1, hw1, agg1);
    k_gat1_fin<<<(NNODE*HID)/256, 256, 0, stream>>>(agg1, g1b, g1o);
    k_gat2_lin<<<NNODE, OUTCH, 0, stream>>>(g1o, g2w, g2as, g2ad, hw2, als2, ald2);
    k_gat_edge2<<<(NETOT + 255)/256, 256, 0, stream>>>(ei, als2, ald2, ex2, den2);
    k_gat_agg2<<<(NETOT*OUTCH)/256, 256, 0, stream>>>(ei, ex2, den2, hw2, agg2);
    k_final<<<NNODE, OUTCH, 0, stream>>>(agg2, g2b, ffw, ffb, out);
}

// Round 14
// 625.306 us; speedup vs baseline: 2.5428x; 1.9397x over previous
//
#include <hip/hip_runtime.h>
#include <hip/hip_bf16.h>
#include <stdint.h>

// ---------------------------------------------------------------------------
// PFGAT: [B,T,N,F]=[4,8,2048,16] transformer (causal attn over N per (b,t),
// node attn over T-slots, MLP at last slot) -> 2x GATConv -> FFN -> [B,14,N].
// fp32 I/O, fp32 compute, bf16 intermediate storage.
// R14: kill scattered per-thread weight loads. Attn: ch-per-lane Q prologue
// (coalesced wq), NO epilogue (writes CX). New k_h1 MFMA GEMM:
// H1 = [cx|x|0] @ [t_wo^T|skw^T|0] + bias, B staged in LDS per block.
// CX/H1 share one buffer (in-place). Peak ws stays 52 MiB.
// ---------------------------------------------------------------------------

#define BB     4
#define TT     8
#define NN     2048
#define FIN    16
#define HID    128
#define BM     (BB*TT)            // 32 attention slices
#define PROWS  (BM*NN)            // 65536 rows
#define NHEADS 4
#define OUTCH  64
#define OUTF   14
#define NEDGE  32768
#define NEDGEB (NEDGE*BB)         // 131072
#define NNODE  (BB*NN)            // 8192
#define NETOT  (NEDGEB + NNODE)   // 139264 (edges + self loops)

#define TQ     64                 // query tile (rows per block)
#define NTILE  (NN/TQ)            // 32 query tiles per slice

typedef __hip_bfloat16 bf16;
typedef __attribute__((ext_vector_type(8))) short bf16x8;   // MFMA A/B frag
typedef __attribute__((ext_vector_type(4))) float f32x4;    // MFMA C/D frag

__device__ __forceinline__ float b2f(bf16 v){ return __bfloat162float(v); }
__device__ __forceinline__ bf16  f2b(float f){ return __float2bfloat16(f); }

// ---------------------------------------------------------------------------
// K1: per row: LN1 over F=16 -> k,v projections; K row-major, V key-tiled
// (Vt[slice][key>>5][ch][key&31]) so each 32-key slab is 8KB contiguous.
// ---------------------------------------------------------------------------
__global__ void k_kv(const float* __restrict__ x,
                     const float* __restrict__ g1, const float* __restrict__ bb1,
                     const float* __restrict__ wk, const float* __restrict__ bk,
                     const float* __restrict__ wv, const float* __restrict__ bv,
                     int in_off, bf16* __restrict__ K, bf16* __restrict__ Vt)
{
    const int rloc = blockIdx.x;
    const int rin  = rloc + in_off;
    const int h = threadIdx.x;       // 0..127
    __shared__ float xr[FIN], lnv[FIN];
    if (h < FIN) xr[h] = x[(size_t)rin*FIN + h];
    __syncthreads();
    float mu = 0.f;
    #pragma unroll
    for (int f = 0; f < FIN; ++f) mu += xr[f];
    mu *= (1.f/FIN);
    float var = 0.f;
    #pragma unroll
    for (int f = 0; f < FIN; ++f){ float d = xr[f]-mu; var += d*d; }
    var *= (1.f/FIN);
    const float inv = rsqrtf(var + 1e-5f);
    if (h < FIN) lnv[h] = (xr[h]-mu)*inv*g1[h] + bb1[h];
    __syncthreads();
    float ak = bk[h], av = bv[h];
    #pragma unroll
    for (int f = 0; f < FIN; ++f){
        const float l = lnv[f];
        ak += l * wk[f*HID + h];
        av += l * wv[f*HID + h];
    }
    K[(size_t)rloc*HID + h] = f2b(ak);
    const int slice = rloc >> 11;            // 0 in narrow mode
    const int key   = rloc & (NN-1);
    Vt[(((size_t)slice*(NN/32) + (key>>5))*HID + h)*32 + (key&31)] = f2b(av);
}

// ---------------------------------------------------------------------------
// K2 (MFMA flash, no epilogue): blockIdx.x = slice (XCD-stable), blockIdx.y =
// tile rank (0 = biggest, LPT). Prologue: LN1 in-place, Q-projection with
// ch-per-lane mapping (wq reads coalesced + hoisted). Per 32-key step:
// cooperative K/V slab staging -> LDS, S = Q.K^T, mask+exp (no-max softmax),
// P roundtrip, PV. Writes normalized CX (bf16, coalesced). No weight matmul.
// ---------------------------------------------------------------------------
__global__ __launch_bounds__(256)
void k_attn_mfma(const float* __restrict__ x,
                 const bf16* __restrict__ K, const bf16* __restrict__ Vt,
                 const float* __restrict__ g1, const float* __restrict__ bb1,
                 const float* __restrict__ wq, const float* __restrict__ bq,
                 int slice_off, bf16* __restrict__ CX)
{
    const int tile  = (NTILE-1) - (int)blockIdx.y;   // big tiles first
    const int q0    = tile*TQ;
    const int slice = blockIdx.x + slice_off;
    const int t     = threadIdx.x;
    const int w     = t >> 6;            // wave 0..3
    const int lane  = t & 63;
    const int quad  = lane >> 4;
    const int l16   = lane & 15;
    const int wr0   = w*16;              // wave's first local row

    __shared__ float xs [TQ][FIN];                 // x rows; LN1 in-place
    __shared__ bf16  Qs [TQ][136];                 // Q (scaled) bf16; cx later
    __shared__ bf16  Ps [4][16][40];               // per-wave P roundtrip
    __shared__ bf16  Ks [32*136];                  // staged K tile (pad 8)
    __shared__ bf16  Vs [128*40];                  // staged V tile (pad 8)

    // ---- stage x rows ----
    for (int u = t; u < TQ*FIN; u += 256)
        ((float*)xs)[u] = x[((size_t)slice*NN + q0)*FIN + u];
    __syncthreads();
    // ---- LN1 per row, in place ----
    if (t < TQ){
        float mu = 0.f;
        #pragma unroll
        for (int f = 0; f < FIN; ++f) mu += xs[t][f];
        mu *= (1.f/FIN);
        float var = 0.f;
        #pragma unroll
        for (int f = 0; f < FIN; ++f){ float d = xs[t][f]-mu; var += d*d; }
        var *= (1.f/FIN);
        const float inv = rsqrtf(var + 1e-5f);
        #pragma unroll
        for (int f = 0; f < FIN; ++f)
            xs[t][f] = (xs[t][f]-mu)*inv*g1[f] + bb1[f];
    }
    __syncthreads();
    // ---- Q projection, ch-per-lane (wq coalesced, hoisted) ----
    {
        const int ch = t & 127, half = t >> 7;     // rows half*32..+31
        const float scale = 0.08838834764831845f;  // 1/sqrt(128)
        float wqr[FIN];
        #pragma unroll
        for (int f = 0; f < FIN; ++f) wqr[f] = wq[f*HID + ch];
        const float bqv = bq[ch];
        for (int j = 0; j < 32; ++j){
            const int row = half*32 + j;
            const float4 l0 = ((const float4*)&xs[row][0])[0];
            const float4 l1 = ((const float4*)&xs[row][0])[1];
            const float4 l2 = ((const float4*)&xs[row][0])[2];
            const float4 l3 = ((const float4*)&xs[row][0])[3];
            float a = bqv;
            a += l0.x*wqr[0]  + l0.y*wqr[1]  + l0.z*wqr[2]  + l0.w*wqr[3];
            a += l1.x*wqr[4]  + l1.y*wqr[5]  + l1.z*wqr[6]  + l1.w*wqr[7];
            a += l2.x*wqr[8]  + l2.y*wqr[9]  + l2.z*wqr[10] + l2.w*wqr[11];
            a += l3.x*wqr[12] + l3.y*wqr[13] + l3.z*wqr[14] + l3.w*wqr[15];
            Qs[row][ch] = f2b(a*scale);
        }
    }
    __syncthreads();

    // ---- Q A-frags: A[m=l16][k=quad*8+j], k-step ks*32 ----
    bf16x8 qf[4];
    #pragma unroll
    for (int ks = 0; ks < 4; ++ks)
        qf[ks] = *(const bf16x8*)(const void*)&Qs[wr0 + l16][ks*32 + quad*8];

    f32x4 O[8];
    #pragma unroll
    for (int ct = 0; ct < 8; ++ct) O[ct] = (f32x4){0.f,0.f,0.f,0.f};
    float l_[4] = {0.f,0.f,0.f,0.f};     // per-lane partial row sums

    const size_t kb = (size_t)blockIdx.x * NN * HID;                 // K slice
    const size_t vb = (size_t)blockIdx.x * (size_t)(NN/32) * HID*32; // Vt slice
    const int jend_blk = q0 + TQ - 1;       // block-uniform loop bound
    const int my_jmax  = q0 + wr0 + 15;     // wave-uniform causal bound
    const int brow = q0 + wr0 + quad*4;     // +reg = my global q-row

    for (int j0 = 0; j0 <= jend_blk; j0 += 32){
        // ---- cooperative staging: K slab + V slab, coalesced b128 ----
        {
            const bf16* ksl = K  + kb + (size_t)j0*HID;           // 32x128
            const bf16* vsl = Vt + vb + (size_t)(j0>>5)*(HID*32); // 128x32
            #pragma unroll
            for (int it = 0; it < 2; ++it){
                const int c = t + it*256;          // 512 chunks of 8 bf16
                *(bf16x8*)(void*)&Ks[(c>>4)*136 + (c&15)*8] =
                    *(const bf16x8*)(const void*)(ksl + c*8);
                *(bf16x8*)(void*)&Vs[(c>>2)*40 + (c&3)*8] =
                    *(const bf16x8*)(const void*)(vsl + c*8);
            }
        }
        __syncthreads();

        if (j0 <= my_jmax){              // wave-uniform compute guard
            f32x4 S0 = (f32x4){0.f,0.f,0.f,0.f}, S1 = S0;
            #pragma unroll
            for (int ks = 0; ks < 4; ++ks){
                const bf16x8 kf0 = *(const bf16x8*)(const void*)
                    &Ks[(l16     )*136 + ks*32 + quad*8];
                const bf16x8 kf1 = *(const bf16x8*)(const void*)
                    &Ks[(l16 + 16)*136 + ks*32 + quad*8];
                S0 = __builtin_amdgcn_mfma_f32_16x16x32_bf16(qf[ks], kf0, S0, 0, 0, 0);
                S1 = __builtin_amdgcn_mfma_f32_16x16x32_bf16(qf[ks], kf1, S1, 0, 0, 0);
            }
            const int c0j = j0 + l16, c1j = c0j + 16;
            #pragma unroll
            for (int r = 0; r < 4; ++r){
                const float s0 = (c0j <= brow + r) ? S0[r] : -1e30f;
                const float s1 = (c1j <= brow + r) ? S1[r] : -1e30f;
                const bf16 hb0 = f2b(__expf(s0));
                const bf16 hb1 = f2b(__expf(s1));
                Ps[w][quad*4 + r][l16]      = hb0;
                Ps[w][quad*4 + r][l16 + 16] = hb1;
                l_[r] += b2f(hb0) + b2f(hb1);       // sum the rounded P
            }
            const bf16x8 pf = *(const bf16x8*)(const void*)&Ps[w][l16][quad*8];
            #pragma unroll
            for (int ct = 0; ct < 8; ++ct){
                const bf16x8 vf = *(const bf16x8*)(const void*)
                    &Vs[(ct*16 + l16)*40 + quad*8];
                O[ct] = __builtin_amdgcn_mfma_f32_16x16x32_bf16(pf, vf, O[ct], 0, 0, 0);
            }
        }
        __syncthreads();
    }

    // ---- reduce l, normalize -> Qs (own-wave rows; Q-frags already used) ----
    {
        float inv[4];
        #pragma unroll
        for (int r = 0; r < 4; ++r){
            float rs = l_[r];
            rs += __shfl_xor(rs, 1);
            rs += __shfl_xor(rs, 2);
            rs += __shfl_xor(rs, 4);
            rs += __shfl_xor(rs, 8);
            inv[r] = 1.f/rs;
        }
        #pragma unroll
        for (int ct = 0; ct < 8; ++ct)
        #pragma unroll
        for (int r = 0; r < 4; ++r)
            Qs[wr0 + quad*4 + r][ct*16 + l16] = f2b(O[ct][r]*inv[r]);
    }
    __syncthreads();
    // ---- coalesced CX write ----
    {
        const int row = t >> 2, ch0 = (t & 3)*32;
        bf16* dst = CX + ((size_t)slice*NN + q0 + row)*HID + ch0;
        #pragma unroll
        for (int c = 0; c < 4; ++c)
            *(bf16x8*)(void*)(dst + c*8) =
                *(const bf16x8*)(const void*)&Qs[row][ch0 + c*8];
    }
}

// ---------------------------------------------------------------------------
// K_H1 (MFMA epilogue GEMM): H1 = [cx | x | 0] @ [t_wo^T | skw^T | 0] + bias
// (K=160). Block = 64 rows of one slice; B staged once per block in LDS
// (coalesced reads, one-time transpose scatter). In-place CX -> H1.
// ---------------------------------------------------------------------------
__global__ __launch_bounds__(256)
void k_h1(const float* __restrict__ x,
          const float* __restrict__ t_wo, const float* __restrict__ skw,
          const float* __restrict__ t_bo, const float* __restrict__ skb,
          int slice_off, bf16* __restrict__ CXH1)
{
    const int slice = blockIdx.x + slice_off;
    const int q0    = blockIdx.y * TQ;
    const int t     = threadIdx.x;
    const int w     = t >> 6;
    const int lane  = t & 63;
    const int quad  = lane >> 4;
    const int l16   = lane & 15;
    const int wr0   = w*16;

    __shared__ bf16 Aext[TQ][168];    // [cx(128) | x(16) | 0(16) | pad]
    __shared__ bf16 Bext[HID][168];   // [t_wo^T  | skw^T | 0    | pad]

    // ---- stage A: cx rows (coalesced b128) ----
    {
        const bf16* src = CXH1 + ((size_t)slice*NN + q0)*HID;
        #pragma unroll
        for (int it = 0; it < 4; ++it){
            const int c = t + it*256;                 // 1024 chunks of 8
            *(bf16x8*)(void*)&Aext[c>>4][(c&15)*8] =
                *(const bf16x8*)(const void*)(src + c*8);
        }
    }
    // ---- stage A: x cols 128-143, zeros 144-159 ----
    #pragma unroll
    for (int it = 0; it < 4; ++it){
        const int u = t + it*256;                     // 1024
        const int row = u >> 4, f = u & 15;
        Aext[row][128 + f] = f2b(x[((size_t)slice*NN + q0 + row)*FIN + f]);
        if (row < 16) Aext[(u>>4)|((it&0)<<0)][0] = Aext[row][0]; // no-op keep
    }
    #pragma unroll
    for (int it = 0; it < 4; ++it){
        const int u = t + it*256;                     // 1024 = 64*16
        Aext[u>>4][144 + (u&15)] = f2b(0.f);
    }
    // ---- stage B: t_wo^T (coalesced read, scatter write) ----
    #pragma unroll
    for (int it = 0; it < 16; ++it){
        const int idx = t + it*256;                   // 4096 float4 = 16384 f
        const int c = idx >> 5, ch4 = (idx & 31)*4;
        const float4 v = ((const float4*)t_wo)[idx];
        Bext[ch4+0][c] = f2b(v.x);
        Bext[ch4+1][c] = f2b(v.y);
        Bext[ch4+2][c] = f2b(v.z);
        Bext[ch4+3][c] = f2b(v.w);
    }
    // ---- stage B: skw^T cols 128-143, zeros 144-159 ----
    #pragma unroll
    for (int it = 0; it < 2; ++it){
        const int idx = t + it*256;                   // 512 float4 = 2048 f
        const int f = idx >> 5, ch4 = (idx & 31)*4;
        const float4 v = ((const float4*)skw)[idx];
        Bext[ch4+0][128+f] = f2b(v.x);
        Bext[ch4+1][128+f] = f2b(v.y);
        Bext[ch4+2][128+f] = f2b(v.z);
        Bext[ch4+3][128+f] = f2b(v.w);
    }
    #pragma unroll
    for (int it = 0; it < 8; ++it){
        const int u = t + it*256;                     // 2048 = 128*16
        Bext[u>>4][144 + (u&15)] = f2b(0.f);
    }
    __syncthreads();

    // ---- GEMM: 5 k-steps x 8 n-tiles per wave (rows wr0..wr0+15) ----
    f32x4 O[8];
    #pragma unroll
    for (int ct = 0; ct < 8; ++ct) O[ct] = (f32x4){0.f,0.f,0.f,0.f};
    #pragma unroll
    for (int ks = 0; ks < 5; ++ks){
        const bf16x8 af = *(const bf16x8*)(const void*)&Aext[wr0 + l16][ks*32 + quad*8];
        #pragma unroll
        for (int ct = 0; ct < 8; ++ct){
            const bf16x8 bf = *(const bf16x8*)(const void*)&Bext[ct*16 + l16][ks*32 + quad*8];
            O[ct] = __builtin_amdgcn_mfma_f32_16x16x32_bf16(af, bf, O[ct], 0, 0, 0);
        }
    }
    // ---- bias + C -> Aext (own-wave rows; A-frags fully consumed) ----
    #pragma unroll
    for (int ct = 0; ct < 8; ++ct){
        const int col = ct*16 + l16;
        const float bias = t_bo[col] + skb[col];
        #pragma unroll
        for (int r = 0; r < 4; ++r)
            Aext[wr0 + quad*4 + r][col] = f2b(O[ct][r] + bias);
    }
    __syncthreads();
    // ---- coalesced H1 write (in-place over CX rows) ----
    {
        const int row = t >> 2, ch0 = (t & 3)*32;
        bf16* dst = CXH1 + ((size_t)slice*NN + q0 + row)*HID + ch0;
        #pragma unroll
        for (int c = 0; c < 4; ++c)
            *(bf16x8*)(void*)(dst + c*8) =
                *(const bf16x8*)(const void*)&Aext[row][ch0 + c*8];
    }
}

// ---------------------------------------------------------------------------
// K3: per (b,s): load h1[m] (all 8 m), LN2, node attention (q for m=7 only),
// LN3, MLP -> node feature [128] fp32.
// ---------------------------------------------------------------------------
__global__ void k_mix(const bf16* __restrict__ H1,
                      const float* __restrict__ ln2g, const float* __restrict__ ln2b,
                      const float* __restrict__ s_wq, const float* __restrict__ s_bq,
                      const float* __restrict__ s_wk, const float* __restrict__ s_bk,
                      const float* __restrict__ s_wv, const float* __restrict__ s_bv,
                      const float* __restrict__ s_wo, const float* __restrict__ s_bo,
                      const float* __restrict__ ln3g, const float* __restrict__ ln3b,
                      const float* __restrict__ w1, const float* __restrict__ bm1,
                      const float* __restrict__ w2, const float* __restrict__ bm2,
                      float* __restrict__ Hn)
{
    const int blk = blockIdx.x;          // b*NN + s
    const int b = blk >> 11, s = blk & (NN-1);
    const int h = threadIdx.x;           // 0..127
    __shared__ float h1[TT][HID], z2[TT][HID], k2[TT][HID], v2[TT][HID];
    __shared__ float qv[HID], z3s[HID], hls[2*HID];
    __shared__ float scr[TT];
    __shared__ float rb1[HID], rb2[HID];

    #pragma unroll
    for (int m = 0; m < TT; ++m)
        h1[m][h] = b2f(H1[((size_t)(b*TT + m)*NN + s)*HID + h]);
    __syncthreads();

    const float g2v = ln2g[h], b2v = ln2b[h];
    for (int m = 0; m < TT; ++m){
        const float v = h1[m][h];
        rb1[h] = v; rb2[h] = v*v; __syncthreads();
        for (int st = 64; st > 0; st >>= 1){
            if (h < st){ rb1[h] += rb1[h+st]; rb2[h] += rb2[h+st]; }
            __syncthreads();
        }
        const float mu = rb1[0]*(1.f/HID);
        const float var = rb2[0]*(1.f/HID) - mu*mu;
        const float inv = rsqrtf(var + 1e-5f);
        __syncthreads();
        z2[m][h] = (v - mu)*inv*g2v + b2v;
    }
    __syncthreads();

    {
        float ack[TT], acv[TT];
        const float bkv = s_bk[h], bvv = s_bv[h];
        #pragma unroll
        for (int m = 0; m < TT; ++m){ ack[m] = bkv; acv[m] = bvv; }
        for (int c = 0; c < HID; ++c){
            const float wk = s_wk[c*HID + h];
            const float wv = s_wv[c*HID + h];
            #pragma unroll
            for (int m = 0; m < TT; ++m){ ack[m] += z2[m][c]*wk; acv[m] += z2[m][c]*wv; }
        }
        #pragma unroll
        for (int m = 0; m < TT; ++m){ k2[m][h] = ack[m]; v2[m][h] = acv[m]; }
        float aq = s_bq[h];
        for (int c = 0; c < HID; ++c) aq += z2[TT-1][c]*s_wq[c*HID + h];
        qv[h] = aq;
    }
    __syncthreads();

    if (h < TT){
        float d = 0.f;
        for (int c = 0; c < HID; ++c) d += qv[c]*k2[h][c];
        scr[h] = d * 0.08838834764831845f;
    }
    __syncthreads();
    float mx = -1e30f;
    #pragma unroll
    for (int m = 0; m < TT; ++m) mx = fmaxf(mx, scr[m]);
    float p[TT], se = 0.f;
    #pragma unroll
    for (int m = 0; m < TT; ++m){ p[m] = __expf(scr[m]-mx); se += p[m]; }
    const float isum = 1.f/se;
    float c2 = 0.f;
    #pragma unroll
    for (int m = 0; m < TT; ++m) c2 += p[m]*v2[m][h];
    c2 *= isum;
    __syncthreads();
    qv[h] = c2;
    __syncthreads();

    float o = s_bo[h];
    for (int c = 0; c < HID; ++c) o += qv[c]*s_wo[c*HID + h];
    const float h2 = h1[TT-1][h] + o;

    rb1[h] = h2; rb2[h] = h2*h2; __syncthreads();
    for (int st = 64; st > 0; st >>= 1){
        if (h < st){ rb1[h] += rb1[h+st]; rb2[h] += rb2[h+st]; }
        __syncthreads();
    }
    {
        const float mu = rb1[0]*(1.f/HID);
        const float var = rb2[0]*(1.f/HID) - mu*mu;
        const float inv = rsqrtf(var + 1e-5f);
        __syncthreads();
        z3s[h] = (h2 - mu)*inv*ln3g[h] + ln3b[h];
    }
    __syncthreads();

    float hid0 = bm1[h], hid1 = bm1[h+HID];
    for (int c = 0; c < HID; ++c){
        const float z = z3s[c];
        hid0 += z * w1[c*2*HID + h];
        hid1 += z * w1[c*2*HID + h + HID];
    }
    hls[h] = fmaxf(hid0, 0.f); hls[h+HID] = fmaxf(hid1, 0.f);
    __syncthreads();
    float outv = bm2[h] + h2;
    for (int j = 0; j < 2*HID; ++j) outv += hls[j]*w2[j*HID + h];
    Hn[(size_t)(b*NN + s)*HID + h] = outv;
}

// ---------------------------------------------------------------------------
// GAT
// ---------------------------------------------------------------------------
__device__ __forceinline__ void edge_decode(const int* __restrict__ ei, int e,
                                            int& src, int& dst, bool& dropped)
{
    if (e < NEDGEB){
        const int bb = e >> 15, k = e & (NEDGE-1);
        const int s0 = ei[k], d0 = ei[NEDGE + k];
        src = s0 + bb*NN; dst = d0 + bb*NN;
        dropped = (s0 == d0);     // PyG removes pre-existing self loops
    } else { src = dst = e - NEDGEB; dropped = false; }
}

__global__ void k_gat1_lin(const float* __restrict__ Hn, const float* __restrict__ W,
                           const float* __restrict__ asrc, const float* __restrict__ adst,
                           bf16* __restrict__ hw, float* __restrict__ als, float* __restrict__ ald)
{
    const int nid = blockIdx.x, c = threadIdx.x;   // 128
    __shared__ float hr[HID], r1[HID], r2[HID];
    hr[c] = Hn[(size_t)nid*HID + c];
    __syncthreads();
    float a = 0.f;
    for (int k = 0; k < HID; ++k) a += hr[k]*W[k*HID + c];
    hw[(size_t)nid*HID + c] = f2b(a);
    r1[c] = a*asrc[c]; r2[c] = a*adst[c];
    __syncthreads();
    for (int st = 16; st > 0; st >>= 1){
        if ((c & 31) < st){ r1[c] += r1[c+st]; r2[c] += r2[c+st]; }
        __syncthreads();
    }
    if ((c & 31) == 0){
        als[nid*NHEADS + (c>>5)] = r1[c];
        ald[nid*NHEADS + (c>>5)] = r2[c];
    }
}

__global__ void k_gat_edge1(const int* __restrict__ ei, const float* __restrict__ als,
                            const float* __restrict__ ald, bf16* __restrict__ ex,
                            float* __restrict__ denom)
{
    const int idx = blockIdx.x*blockDim.x + threadIdx.x;
    if (idx >= NETOT*NHEADS) return;
    const int e = idx >> 2, hd = idx & 3;
    int src, dst; bool drop;
    edge_decode(ei, e, src, dst, drop);
    if (drop){ ex[idx] = f2b(0.f); return; }
    float a = als[src*NHEADS + hd] + ald[dst*NHEADS + hd];
    a = a > 0.f ? a : 0.2f*a;
    const bf16 vb = f2b(__expf(a));
    ex[idx] = vb;
    atomicAdd(&denom[dst*NHEADS + hd], b2f(vb));
}

__global__ void k_gat_agg1(const int* __restrict__ ei, const bf16* __restrict__ ex,
                           const float* __restrict__ denom, const bf16* __restrict__ hw,
                           float* __restrict__ agg)
{
    const int t = blockIdx.x*blockDim.x + threadIdx.x;   // NETOT*128
    const int e = t >> 7, c = t & 127;
    if (e >= NETOT) return;
    const float x = b2f(ex[e*NHEADS + (c>>5)]);
    if (x == 0.f) return;
    int src, dst; bool drop;
    edge_decode(ei, e, src, dst, drop);
    const float w = x / denom[dst*NHEADS + (c>>5)];
    atomicAdd(&agg[(size_t)dst*HID + c], w * b2f(hw[(size_t)src*HID + c]));
}

__global__ void k_gat1_fin(const float* __restrict__ agg, const float* __restrict__ bias,
                           bf16* __restrict__ g1)
{
    const int t = blockIdx.x*blockDim.x + threadIdx.x;
    if (t >= NNODE*HID) return;
    const float v = agg[t] + bias[t & 127];
    g1[t] = f2b(v > 0.f ? v : expm1f(v));    // elu
}

__global__ void k_gat2_lin(const bf16* __restrict__ g1, const float* __restrict__ W,
                           const float* __restrict__ asrc, const float* __restrict__ adst,
                           bf16* __restrict__ hw2, float* __restrict__ al2s, float* __restrict__ al2d)
{
    const int nid = blockIdx.x, c = threadIdx.x;    // 64 threads = 1 wave
    __shared__ float hr[HID];
    hr[c] = b2f(g1[(size_t)nid*HID + c]);
    hr[c+64] = b2f(g1[(size_t)nid*HID + c + 64]);
    __syncthreads();
    float a = 0.f;
    for (int k = 0; k < HID; ++k) a += hr[k]*W[k*OUTCH + c];
    hw2[(size_t)nid*OUTCH + c] = f2b(a);
    float s1 = a*asrc[c], s2 = a*adst[c];
    #pragma unroll
    for (int off = 32; off > 0; off >>= 1){
        s1 += __shfl_down(s1, off);
        s2 += __shfl_down(s2, off);
    }
    if (c == 0){ al2s[nid] = s1; al2d[nid] = s2; }
}

__global__ void k_gat_edge2(const int* __restrict__ ei, const float* __restrict__ als,
                            const float* __restrict__ ald, bf16* __restrict__ ex,
                            float* __restrict__ denom)
{
    const int e = blockIdx.x*blockDim.x + threadIdx.x;
    if (e >= NETOT) return;
    int src, dst; bool drop;
    edge_decode(ei, e, src, dst, drop);
    if (drop){ ex[e] = f2b(0.f); return; }
    float a = als[src] + ald[dst];
    a = a > 0.f ? a : 0.2f*a;
    const bf16 vb = f2b(__expf(a));
    ex[e] = vb;
    atomicAdd(&denom[dst], b2f(vb));
}

__global__ void k_gat_agg2(const int* __restrict__ ei, const bf16* __restrict__ ex,
                           const float* __restrict__ denom, const bf16* __restrict__ hw2,
                           float* __restrict__ agg)
{
    const int t = blockIdx.x*blockDim.x + threadIdx.x;   // NETOT*64
    const int e = t >> 6, c = t & 63;
    if (e >= NETOT) return;
    const float x = b2f(ex[e]);
    if (x == 0.f) return;
    int src, dst; bool drop;
    edge_decode(ei, e, src, dst, drop);
    const float w = x / denom[dst];
    atomicAdd(&agg[(size_t)dst*OUTCH + c], w * b2f(hw2[(size_t)src*OUTCH + c]));
}

__global__ void k_final(const float* __restrict__ agg2, const float* __restrict__ g2b,
                        const float* __restrict__ fw, const float* __restrict__ fb,
                        float* __restrict__ out)
{
    const int nid = blockIdx.x, c = threadIdx.x;    // 64
    __shared__ float g[OUTCH];
    g[c] = agg2[(size_t)nid*OUTCH + c] + g2b[c];
    __syncthreads();
    if (c < OUTF){
        float o = fb[c];
        for (int k = 0; k < OUTCH; ++k) o += g[k]*fw[k*OUTF + c];
        const int b = nid >> 11, n = nid & (NN-1);
        out[((size_t)b*OUTF + c)*NN + n] = o;
    }
}

// ---------------------------------------------------------------------------
extern "C" void kernel_launch(void* const* d_in, const int* in_sizes, int n_in,
                              void* d_out, int out_size, void* d_ws, size_t ws_size,
                              hipStream_t stream)
{
    const float* x    = (const float*)d_in[0];
    const int*  ei    = (const int*)d_in[1];
    const float* ln1g = (const float*)d_in[2];  const float* ln1b = (const float*)d_in[3];
    const float* t_wq = (const float*)d_in[4];  const float* t_bq = (const float*)d_in[5];
    const float* t_wk = (const float*)d_in[6];  const float* t_bk = (const float*)d_in[7];
    const float* t_wv = (const float*)d_in[8];  const float* t_bv = (const float*)d_in[9];
    const float* t_wo = (const float*)d_in[10]; const float* t_bo = (const float*)d_in[11];
    const float* skw  = (const float*)d_in[12]; const float* skb  = (const float*)d_in[13];
    const float* ln2g = (const float*)d_in[14]; const float* ln2b = (const float*)d_in[15];
    const float* s_wq = (const float*)d_in[16]; const float* s_bq = (const float*)d_in[17];
    const float* s_wk = (const float*)d_in[18]; const float* s_bk = (const float*)d_in[19];
    const float* s_wv = (const float*)d_in[20]; const float* s_bv = (const float*)d_in[21];
    const float* s_wo = (const float*)d_in[22]; const float* s_bo = (const float*)d_in[23];
    const float* ln3g = (const float*)d_in[24]; const float* ln3b = (const float*)d_in[25];
    const float* w1   = (const float*)d_in[26]; const float* b1   = (const float*)d_in[27];
    const float* w2   = (const float*)d_in[28]; const float* b2   = (const float*)d_in[29];
    const float* g1w  = (const float*)d_in[30];
    const float* g1as = (const float*)d_in[31]; const float* g1ad = (const float*)d_in[32];
    const float* g1b  = (const float*)d_in[33];
    const float* g2w  = (const float*)d_in[34];
    const float* g2as = (const float*)d_in[35]; const float* g2ad = (const float*)d_in[36];
    const float* g2b  = (const float*)d_in[37];
    const float* ffw  = (const float*)d_in[38]; const float* ffb  = (const float*)d_in[39];
    float* out = (float*)d_out;

    const size_t MiB = 1024u*1024u;
    const bool wide = ws_size >= 52*MiB;   // K(16)+Vt(16)+CXH1(16)+Hn(4)

    char* base = (char*)d_ws;
    bf16 *Kb, *Vtb, *CXH1;
    float* Hn;
    char* gat_base;
    if (wide){
        Kb   = (bf16*)(base + 0*MiB);      // 16 MiB (all 32 slices, row-major)
        Vtb  = (bf16*)(base + 16*MiB);     // 16 MiB ([slice][kt][ch][32])
        CXH1 = (bf16*)(base + 32*MiB);     // 16 MiB (CX then H1, in place)
        Hn   = (float*)(base + 48*MiB);    // 4 MiB
        gat_base = base;                   // aliases Kb/Vtb (dead after k_h1)
    } else {
        CXH1 = (bf16*)(base + 0*MiB);      // 16 MiB
        Hn   = (float*)(base + 16*MiB);    // 4 MiB
        Kb   = (bf16*)(base + 20*MiB);     // 0.5 MiB (one slice)
        Vtb  = (bf16*)(base + 20*MiB + 512u*1024u);
        gat_base = base;                   // aliases CXH1 (dead after k_mix)
    }
    // GAT scratch (~12.9 MiB) inside gat_base
    char* w = gat_base;
    auto alloc = [&](size_t bytes){ void* p = (void*)w; w += (bytes + 255) & ~(size_t)255; return p; };
    bf16*  hw1  = (bf16*) alloc((size_t)NNODE*HID*sizeof(bf16));
    float* als1 = (float*)alloc((size_t)NNODE*NHEADS*sizeof(float));
    float* ald1 = (float*)alloc((size_t)NNODE*NHEADS*sizeof(float));
    bf16*  ex1  = (bf16*) alloc((size_t)NETOT*NHEADS*sizeof(bf16));
    float* den1 = (float*)alloc((size_t)NNODE*NHEADS*sizeof(float));
    float* agg1 = (float*)alloc((size_t)NNODE*HID*sizeof(float));
    bf16*  g1o  = (bf16*) alloc((size_t)NNODE*HID*sizeof(bf16));
    bf16*  hw2  = (bf16*) alloc((size_t)NNODE*OUTCH*sizeof(bf16));
    float* als2 = (float*)alloc((size_t)NNODE*sizeof(float));
    float* ald2 = (float*)alloc((size_t)NNODE*sizeof(float));
    bf16*  ex2  = (bf16*) alloc((size_t)NETOT*sizeof(bf16));
    float* den2 = (float*)alloc((size_t)NNODE*sizeof(float));
    float* agg2 = (float*)alloc((size_t)NNODE*OUTCH*sizeof(float));

    // ---- trunk ----
    if (wide){
        k_kv<<<PROWS, HID, 0, stream>>>(x, ln1g, ln1b, t_wk, t_bk, t_wv, t_bv, 0, Kb, Vtb);
        k_attn_mfma<<<dim3(BM, NTILE), 256, 0, stream>>>(x, Kb, Vtb, ln1g, ln1b,
                                                         t_wq, t_bq, 0, CXH1);
        k_h1<<<dim3(BM, NTILE), 256, 0, stream>>>(x, t_wo, skw, t_bo, skb, 0, CXH1);
    } else {
        for (int s = 0; s < BM; ++s){
            k_kv<<<NN, HID, 0, stream>>>(x, ln1g, ln1b, t_wk, t_bk, t_wv, t_bv, s*NN, Kb, Vtb);
            k_attn_mfma<<<dim3(1, NTILE), 256, 0, stream>>>(x, Kb, Vtb, ln1g, ln1b,
                                                            t_wq, t_bq, s, CXH1);
        }
        k_h1<<<dim3(BM, NTILE), 256, 0, stream>>>(x, t_wo, skw, t_bo, skb, 0, CXH1);
    }
    k_mix<<<BB*NN, HID, 0, stream>>>(CXH1, ln2g, ln2b, s_wq, s_bq, s_wk, s_bk,
                                     s_wv, s_bv, s_wo, s_bo, ln3g, ln3b,
                                     w1, b1, w2, b2, Hn);

    // ---- GAT (accumulators zeroed after k_mix; region was dead/poisoned) ----
    hipMemsetAsync(den1, 0, (size_t)NNODE*NHEADS*sizeof(float), stream);
    hipMemsetAsync(agg1, 0, (size_t)NNODE*HID*sizeof(float), stream);
    hipMemsetAsync(den2, 0, (size_t)NNODE*sizeof(float), stream);
    hipMemsetAsync(agg2, 0, (size_t)NNODE*OUTCH*sizeof(float), stream);

    k_gat1_lin<<<NNODE, HID, 0, stream>>>(Hn, g1w, g1as, g1ad, hw1, als1, ald1);
    k_gat_edge1<<<(NETOT*NHEADS + 255)/256, 256, 0, stream>>>(ei, als1, ald1, ex1, den1);
    k_gat_agg1<<<(NETOT*HID)/256, 256, 0, stream>>>(ei, ex1, den1, hw1, agg1);
    k_gat1_fin<<<(NNODE*HID)/256, 256, 0, stream>>>(agg1, g1b, g1o);
    k_gat2_lin<<<NNODE, OUTCH, 0, stream>>>(g1o, g2w, g2as, g2ad, hw2, als2, ald2);
    k_gat_edge2<<<(NETOT + 255)/256, 256, 0, stream>>>(ei, als2, ald2, ex2, den2);
    k_gat_agg2<<<(NETOT*OUTCH)/256, 256, 0, stream>>>(ei, ex2, den2, hw2, agg2);
    k_final<<<NNODE, OUTCH, 0, stream>>>(agg2, g2b, ffw, ffb, out);
}

// Round 15
// 612.344 us; speedup vs baseline: 2.5966x; 1.0212x over previous
//
#include <hip/hip_runtime.h>
#include <hip/hip_bf16.h>
#include <stdint.h>

// ---------------------------------------------------------------------------
// PFGAT: [B,T,N,F]=[4,8,2048,16] transformer (causal attn over N per (b,t),
// node attn over T-slots, MLP at last slot) -> 2x GATConv -> FFN -> [B,14,N].
// fp32 I/O, fp32 compute, bf16 intermediate storage.
// R15: k_mix rewrite: 4 nodes/block (512 thr, L1 weight dedup -> L2 weight
// traffic /4) + shfl-based LN2/LN3 (12 barriers/block vs ~130/node).
// Attn/k_h1/GAT unchanged from R14.
// ---------------------------------------------------------------------------

#define BB     4
#define TT     8
#define NN     2048
#define FIN    16
#define HID    128
#define BM     (BB*TT)            // 32 attention slices
#define PROWS  (BM*NN)            // 65536 rows
#define NHEADS 4
#define OUTCH  64
#define OUTF   14
#define NEDGE  32768
#define NEDGEB (NEDGE*BB)         // 131072
#define NNODE  (BB*NN)            // 8192
#define NETOT  (NEDGEB + NNODE)   // 139264 (edges + self loops)

#define TQ     64                 // query tile (rows per block)
#define NTILE  (NN/TQ)            // 32 query tiles per slice

typedef __hip_bfloat16 bf16;
typedef __attribute__((ext_vector_type(8))) short bf16x8;   // MFMA A/B frag
typedef __attribute__((ext_vector_type(4))) float f32x4;    // MFMA C/D frag

__device__ __forceinline__ float b2f(bf16 v){ return __bfloat162float(v); }
__device__ __forceinline__ bf16  f2b(float f){ return __float2bfloat16(f); }

// ---------------------------------------------------------------------------
// K1: per row: LN1 over F=16 -> k,v projections; K row-major, V key-tiled
// (Vt[slice][key>>5][ch][key&31]) so each 32-key slab is 8KB contiguous.
// ---------------------------------------------------------------------------
__global__ void k_kv(const float* __restrict__ x,
                     const float* __restrict__ g1, const float* __restrict__ bb1,
                     const float* __restrict__ wk, const float* __restrict__ bk,
                     const float* __restrict__ wv, const float* __restrict__ bv,
                     int in_off, bf16* __restrict__ K, bf16* __restrict__ Vt)
{
    const int rloc = blockIdx.x;
    const int rin  = rloc + in_off;
    const int h = threadIdx.x;       // 0..127
    __shared__ float xr[FIN], lnv[FIN];
    if (h < FIN) xr[h] = x[(size_t)rin*FIN + h];
    __syncthreads();
    float mu = 0.f;
    #pragma unroll
    for (int f = 0; f < FIN; ++f) mu += xr[f];
    mu *= (1.f/FIN);
    float var = 0.f;
    #pragma unroll
    for (int f = 0; f < FIN; ++f){ float d = xr[f]-mu; var += d*d; }
    var *= (1.f/FIN);
    const float inv = rsqrtf(var + 1e-5f);
    if (h < FIN) lnv[h] = (xr[h]-mu)*inv*g1[h] + bb1[h];
    __syncthreads();
    float ak = bk[h], av = bv[h];
    #pragma unroll
    for (int f = 0; f < FIN; ++f){
        const float l = lnv[f];
        ak += l * wk[f*HID + h];
        av += l * wv[f*HID + h];
    }
    K[(size_t)rloc*HID + h] = f2b(ak);
    const int slice = rloc >> 11;            // 0 in narrow mode
    const int key   = rloc & (NN-1);
    Vt[(((size_t)slice*(NN/32) + (key>>5))*HID + h)*32 + (key&31)] = f2b(av);
}

// ---------------------------------------------------------------------------
// K2 (MFMA flash, no epilogue): blockIdx.x = slice (XCD-stable), blockIdx.y =
// tile rank (0 = biggest, LPT). Prologue: LN1 in-place, Q-projection with
// ch-per-lane mapping (wq reads coalesced + hoisted). Per 32-key step:
// cooperative K/V slab staging -> LDS, S = Q.K^T, mask+exp (no-max softmax),
// P roundtrip, PV. Writes normalized CX (bf16, coalesced).
// ---------------------------------------------------------------------------
__global__ __launch_bounds__(256)
void k_attn_mfma(const float* __restrict__ x,
                 const bf16* __restrict__ K, const bf16* __restrict__ Vt,
                 const float* __restrict__ g1, const float* __restrict__ bb1,
                 const float* __restrict__ wq, const float* __restrict__ bq,
                 int slice_off, bf16* __restrict__ CX)
{
    const int tile  = (NTILE-1) - (int)blockIdx.y;   // big tiles first
    const int q0    = tile*TQ;
    const int slice = blockIdx.x + slice_off;
    const int t     = threadIdx.x;
    const int w     = t >> 6;            // wave 0..3
    const int lane  = t & 63;
    const int quad  = lane >> 4;
    const int l16   = lane & 15;
    const int wr0   = w*16;              // wave's first local row

    __shared__ float xs [TQ][FIN];                 // x rows; LN1 in-place
    __shared__ bf16  Qs [TQ][136];                 // Q (scaled) bf16; cx later
    __shared__ bf16  Ps [4][16][40];               // per-wave P roundtrip
    __shared__ bf16  Ks [32*136];                  // staged K tile (pad 8)
    __shared__ bf16  Vs [128*40];                  // staged V tile (pad 8)

    for (int u = t; u < TQ*FIN; u += 256)
        ((float*)xs)[u] = x[((size_t)slice*NN + q0)*FIN + u];
    __syncthreads();
    if (t < TQ){
        float mu = 0.f;
        #pragma unroll
        for (int f = 0; f < FIN; ++f) mu += xs[t][f];
        mu *= (1.f/FIN);
        float var = 0.f;
        #pragma unroll
        for (int f = 0; f < FIN; ++f){ float d = xs[t][f]-mu; var += d*d; }
        var *= (1.f/FIN);
        const float inv = rsqrtf(var + 1e-5f);
        #pragma unroll
        for (int f = 0; f < FIN; ++f)
            xs[t][f] = (xs[t][f]-mu)*inv*g1[f] + bb1[f];
    }
    __syncthreads();
    {
        const int ch = t & 127, half = t >> 7;     // rows half*32..+31
        const float scale = 0.08838834764831845f;  // 1/sqrt(128)
        float wqr[FIN];
        #pragma unroll
        for (int f = 0; f < FIN; ++f) wqr[f] = wq[f*HID + ch];
        const float bqv = bq[ch];
        for (int j = 0; j < 32; ++j){
            const int row = half*32 + j;
            const float4 l0 = ((const float4*)&xs[row][0])[0];
            const float4 l1 = ((const float4*)&xs[row][0])[1];
            const float4 l2 = ((const float4*)&xs[row][0])[2];
            const float4 l3 = ((const float4*)&xs[row][0])[3];
            float a = bqv;
            a += l0.x*wqr[0]  + l0.y*wqr[1]  + l0.z*wqr[2]  + l0.w*wqr[3];
            a += l1.x*wqr[4]  + l1.y*wqr[5]  + l1.z*wqr[6]  + l1.w*wqr[7];
            a += l2.x*wqr[8]  + l2.y*wqr[9]  + l2.z*wqr[10] + l2.w*wqr[11];
            a += l3.x*wqr[12] + l3.y*wqr[13] + l3.z*wqr[14] + l3.w*wqr[15];
            Qs[row][ch] = f2b(a*scale);
        }
    }
    __syncthreads();

    bf16x8 qf[4];
    #pragma unroll
    for (int ks = 0; ks < 4; ++ks)
        qf[ks] = *(const bf16x8*)(const void*)&Qs[wr0 + l16][ks*32 + quad*8];

    f32x4 O[8];
    #pragma unroll
    for (int ct = 0; ct < 8; ++ct) O[ct] = (f32x4){0.f,0.f,0.f,0.f};
    float l_[4] = {0.f,0.f,0.f,0.f};

    const size_t kb = (size_t)blockIdx.x * NN * HID;
    const size_t vb = (size_t)blockIdx.x * (size_t)(NN/32) * HID*32;
    const int jend_blk = q0 + TQ - 1;
    const int my_jmax  = q0 + wr0 + 15;
    const int brow = q0 + wr0 + quad*4;

    for (int j0 = 0; j0 <= jend_blk; j0 += 32){
        {
            const bf16* ksl = K  + kb + (size_t)j0*HID;
            const bf16* vsl = Vt + vb + (size_t)(j0>>5)*(HID*32);
            #pragma unroll
            for (int it = 0; it < 2; ++it){
                const int c = t + it*256;
                *(bf16x8*)(void*)&Ks[(c>>4)*136 + (c&15)*8] =
                    *(const bf16x8*)(const void*)(ksl + c*8);
                *(bf16x8*)(void*)&Vs[(c>>2)*40 + (c&3)*8] =
                    *(const bf16x8*)(const void*)(vsl + c*8);
            }
        }
        __syncthreads();

        if (j0 <= my_jmax){
            f32x4 S0 = (f32x4){0.f,0.f,0.f,0.f}, S1 = S0;
            #pragma unroll
            for (int ks = 0; ks < 4; ++ks){
                const bf16x8 kf0 = *(const bf16x8*)(const void*)
                    &Ks[(l16     )*136 + ks*32 + quad*8];
                const bf16x8 kf1 = *(const bf16x8*)(const void*)
                    &Ks[(l16 + 16)*136 + ks*32 + quad*8];
                S0 = __builtin_amdgcn_mfma_f32_16x16x32_bf16(qf[ks], kf0, S0, 0, 0, 0);
                S1 = __builtin_amdgcn_mfma_f32_16x16x32_bf16(qf[ks], kf1, S1, 0, 0, 0);
            }
            const int c0j = j0 + l16, c1j = c0j + 16;
            #pragma unroll
            for (int r = 0; r < 4; ++r){
                const float s0 = (c0j <= brow + r) ? S0[r] : -1e30f;
                const float s1 = (c1j <= brow + r) ? S1[r] : -1e30f;
                const bf16 hb0 = f2b(__expf(s0));
                const bf16 hb1 = f2b(__expf(s1));
                Ps[w][quad*4 + r][l16]      = hb0;
                Ps[w][quad*4 + r][l16 + 16] = hb1;
                l_[r] += b2f(hb0) + b2f(hb1);
            }
            const bf16x8 pf = *(const bf16x8*)(const void*)&Ps[w][l16][quad*8];
            #pragma unroll
            for (int ct = 0; ct < 8; ++ct){
                const bf16x8 vf = *(const bf16x8*)(const void*)
                    &Vs[(ct*16 + l16)*40 + quad*8];
                O[ct] = __builtin_amdgcn_mfma_f32_16x16x32_bf16(pf, vf, O[ct], 0, 0, 0);
            }
        }
        __syncthreads();
    }

    {
        float inv[4];
        #pragma unroll
        for (int r = 0; r < 4; ++r){
            float rs = l_[r];
            rs += __shfl_xor(rs, 1);
            rs += __shfl_xor(rs, 2);
            rs += __shfl_xor(rs, 4);
            rs += __shfl_xor(rs, 8);
            inv[r] = 1.f/rs;
        }
        #pragma unroll
        for (int ct = 0; ct < 8; ++ct)
        #pragma unroll
        for (int r = 0; r < 4; ++r)
            Qs[wr0 + quad*4 + r][ct*16 + l16] = f2b(O[ct][r]*inv[r]);
    }
    __syncthreads();
    {
        const int row = t >> 2, ch0 = (t & 3)*32;
        bf16* dst = CX + ((size_t)slice*NN + q0 + row)*HID + ch0;
        #pragma unroll
        for (int c = 0; c < 4; ++c)
            *(bf16x8*)(void*)(dst + c*8) =
                *(const bf16x8*)(const void*)&Qs[row][ch0 + c*8];
    }
}

// ---------------------------------------------------------------------------
// K_H1 (MFMA epilogue GEMM): H1 = [cx | x | 0] @ [t_wo^T | skw^T | 0] + bias
// (K=160). In-place CX -> H1.
// ---------------------------------------------------------------------------
__global__ __launch_bounds__(256)
void k_h1(const float* __restrict__ x,
          const float* __restrict__ t_wo, const float* __restrict__ skw,
          const float* __restrict__ t_bo, const float* __restrict__ skb,
          int slice_off, bf16* __restrict__ CXH1)
{
    const int slice = blockIdx.x + slice_off;
    const int q0    = blockIdx.y * TQ;
    const int t     = threadIdx.x;
    const int w     = t >> 6;
    const int lane  = t & 63;
    const int quad  = lane >> 4;
    const int l16   = lane & 15;
    const int wr0   = w*16;

    __shared__ bf16 Aext[TQ][168];    // [cx(128) | x(16) | 0(16) | pad]
    __shared__ bf16 Bext[HID][168];   // [t_wo^T  | skw^T | 0    | pad]

    {
        const bf16* src = CXH1 + ((size_t)slice*NN + q0)*HID;
        #pragma unroll
        for (int it = 0; it < 4; ++it){
            const int c = t + it*256;
            *(bf16x8*)(void*)&Aext[c>>4][(c&15)*8] =
                *(const bf16x8*)(const void*)(src + c*8);
        }
    }
    #pragma unroll
    for (int it = 0; it < 4; ++it){
        const int u = t + it*256;
        const int row = u >> 4, f = u & 15;
        Aext[row][128 + f] = f2b(x[((size_t)slice*NN + q0 + row)*FIN + f]);
    }
    #pragma unroll
    for (int it = 0; it < 4; ++it){
        const int u = t + it*256;
        Aext[u>>4][144 + (u&15)] = f2b(0.f);
    }
    #pragma unroll
    for (int it = 0; it < 16; ++it){
        const int idx = t + it*256;
        const int c = idx >> 5, ch4 = (idx & 31)*4;
        const float4 v = ((const float4*)t_wo)[idx];
        Bext[ch4+0][c] = f2b(v.x);
        Bext[ch4+1][c] = f2b(v.y);
        Bext[ch4+2][c] = f2b(v.z);
        Bext[ch4+3][c] = f2b(v.w);
    }
    #pragma unroll
    for (int it = 0; it < 2; ++it){
        const int idx = t + it*256;
        const int f = idx >> 5, ch4 = (idx & 31)*4;
        const float4 v = ((const float4*)skw)[idx];
        Bext[ch4+0][128+f] = f2b(v.x);
        Bext[ch4+1][128+f] = f2b(v.y);
        Bext[ch4+2][128+f] = f2b(v.z);
        Bext[ch4+3][128+f] = f2b(v.w);
    }
    #pragma unroll
    for (int it = 0; it < 8; ++it){
        const int u = t + it*256;
        Bext[u>>4][144 + (u&15)] = f2b(0.f);
    }
    __syncthreads();

    f32x4 O[8];
    #pragma unroll
    for (int ct = 0; ct < 8; ++ct) O[ct] = (f32x4){0.f,0.f,0.f,0.f};
    #pragma unroll
    for (int ks = 0; ks < 5; ++ks){
        const bf16x8 af = *(const bf16x8*)(const void*)&Aext[wr0 + l16][ks*32 + quad*8];
        #pragma unroll
        for (int ct = 0; ct < 8; ++ct){
            const bf16x8 bf = *(const bf16x8*)(const void*)&Bext[ct*16 + l16][ks*32 + quad*8];
            O[ct] = __builtin_amdgcn_mfma_f32_16x16x32_bf16(af, bf, O[ct], 0, 0, 0);
        }
    }
    #pragma unroll
    for (int ct = 0; ct < 8; ++ct){
        const int col = ct*16 + l16;
        const float bias = t_bo[col] + skb[col];
        #pragma unroll
        for (int r = 0; r < 4; ++r)
            Aext[wr0 + quad*4 + r][col] = f2b(O[ct][r] + bias);
    }
    __syncthreads();
    {
        const int row = t >> 2, ch0 = (t & 3)*32;
        bf16* dst = CXH1 + ((size_t)slice*NN + q0 + row)*HID + ch0;
        #pragma unroll
        for (int c = 0; c < 4; ++c)
            *(bf16x8*)(void*)(dst + c*8) =
                *(const bf16x8*)(const void*)&Aext[row][ch0 + c*8];
    }
}

// ---------------------------------------------------------------------------
// K3 (R15): 4 nodes per block (512 thr; 4 lockstep groups -> L1 weight
// dedup). Shfl-based LN2 (all 8 m in parallel, 16-lane groups) and LN3
// (per-wave shfl + 2-value LDS combine). Logic otherwise identical.
// ---------------------------------------------------------------------------
__global__ __launch_bounds__(512)
void k_mix(const bf16* __restrict__ H1,
           const float* __restrict__ ln2g, const float* __restrict__ ln2b,
           const float* __restrict__ s_wq, const float* __restrict__ s_bq,
           const float* __restrict__ s_wk, const float* __restrict__ s_bk,
           const float* __restrict__ s_wv, const float* __restrict__ s_bv,
           const float* __restrict__ s_wo, const float* __restrict__ s_bo,
           const float* __restrict__ ln3g, const float* __restrict__ ln3b,
           const float* __restrict__ w1, const float* __restrict__ bm1,
           const float* __restrict__ w2, const float* __restrict__ bm2,
           float* __restrict__ Hn)
{
    const int g  = threadIdx.x >> 7;          // node slot 0..3
    const int h  = threadIdx.x & 127;
    const int blk = blockIdx.x*4 + g;         // b*NN + s
    const int b = blk >> 11, s = blk & (NN-1);

    __shared__ float h1[4][TT][HID], z2[4][TT][HID], k2[4][TT][HID], v2[4][TT][HID];
    __shared__ float qv[4][HID], z3s[4][HID], hls[4][2*HID];
    __shared__ float scr[4][TT];
    __shared__ float mu_s[4][TT], inv_s[4][TT];
    __shared__ float red2[4][2][2];           // [g][wave-in-group][sum,sq]

    #pragma unroll
    for (int m = 0; m < TT; ++m)
        h1[g][m][h] = b2f(H1[((size_t)(b*TT + m)*NN + s)*HID + h]);
    __syncthreads();

    // ---- LN2 stats: all 8 m in parallel (16-lane shfl groups) ----
    {
        const int m = h >> 4, l16 = h & 15;
        float sum = 0.f, sq = 0.f;
        #pragma unroll
        for (int j = 0; j < 8; ++j){
            const float v = h1[g][m][l16 + 16*j];
            sum += v; sq += v*v;
        }
        sum += __shfl_xor(sum, 1); sq += __shfl_xor(sq, 1);
        sum += __shfl_xor(sum, 2); sq += __shfl_xor(sq, 2);
        sum += __shfl_xor(sum, 4); sq += __shfl_xor(sq, 4);
        sum += __shfl_xor(sum, 8); sq += __shfl_xor(sq, 8);
        if (l16 == 0){
            const float mu = sum*(1.f/HID);
            const float var = sq*(1.f/HID) - mu*mu;
            mu_s[g][m] = mu;
            inv_s[g][m] = rsqrtf(var + 1e-5f);
        }
    }
    __syncthreads();
    {
        const float g2v = ln2g[h], b2v = ln2b[h];
        #pragma unroll
        for (int m = 0; m < TT; ++m)
            z2[g][m][h] = (h1[g][m][h] - mu_s[g][m])*inv_s[g][m]*g2v + b2v;
    }
    __syncthreads();

    // ---- k2, v2 for all m; q for m=7 only ----
    {
        float ack[TT], acv[TT];
        const float bkv = s_bk[h], bvv = s_bv[h];
        #pragma unroll
        for (int m = 0; m < TT; ++m){ ack[m] = bkv; acv[m] = bvv; }
        for (int c = 0; c < HID; ++c){
            const float wk = s_wk[c*HID + h];
            const float wv = s_wv[c*HID + h];
            #pragma unroll
            for (int m = 0; m < TT; ++m){ ack[m] += z2[g][m][c]*wk; acv[m] += z2[g][m][c]*wv; }
        }
        #pragma unroll
        for (int m = 0; m < TT; ++m){ k2[g][m][h] = ack[m]; v2[g][m][h] = acv[m]; }
        float aq = s_bq[h];
        for (int c = 0; c < HID; ++c) aq += z2[g][TT-1][c]*s_wq[c*HID + h];
        qv[g][h] = aq;
    }
    __syncthreads();

    if (h < TT){
        float d = 0.f;
        for (int c = 0; c < HID; ++c) d += qv[g][c]*k2[g][h][c];
        scr[g][h] = d * 0.08838834764831845f;
    }
    __syncthreads();
    float mx = -1e30f;
    #pragma unroll
    for (int m = 0; m < TT; ++m) mx = fmaxf(mx, scr[g][m]);
    float p[TT], se = 0.f;
    #pragma unroll
    for (int m = 0; m < TT; ++m){ p[m] = __expf(scr[g][m]-mx); se += p[m]; }
    const float isum = 1.f/se;
    float c2 = 0.f;
    #pragma unroll
    for (int m = 0; m < TT; ++m) c2 += p[m]*v2[g][m][h];
    c2 *= isum;
    __syncthreads();
    qv[g][h] = c2;          // reuse qv as ctx2
    __syncthreads();

    float o = s_bo[h];
    for (int c = 0; c < HID; ++c) o += qv[g][c]*s_wo[c*HID + h];
    const float h2 = h1[g][TT-1][h] + o;

    // ---- LN3: per-wave shfl + cross-wave combine ----
    {
        float sum = h2, sq = h2*h2;
        #pragma unroll
        for (int off = 1; off < 64; off <<= 1){
            sum += __shfl_xor(sum, off);
            sq  += __shfl_xor(sq,  off);
        }
        const int wv = (threadIdx.x >> 6) & 1;
        if ((threadIdx.x & 63) == 0){ red2[g][wv][0] = sum; red2[g][wv][1] = sq; }
    }
    __syncthreads();
    {
        const float tsum = red2[g][0][0] + red2[g][1][0];
        const float tsq  = red2[g][0][1] + red2[g][1][1];
        const float mu = tsum*(1.f/HID);
        const float var = tsq*(1.f/HID) - mu*mu;
        const float inv = rsqrtf(var + 1e-5f);
        z3s[g][h] = (h2 - mu)*inv*ln3g[h] + ln3b[h];
    }
    __syncthreads();

    float hid0 = bm1[h], hid1 = bm1[h+HID];
    for (int c = 0; c < HID; ++c){
        const float z = z3s[g][c];
        hid0 += z * w1[c*2*HID + h];
        hid1 += z * w1[c*2*HID + h + HID];
    }
    hls[g][h] = fmaxf(hid0, 0.f); hls[g][h+HID] = fmaxf(hid1, 0.f);
    __syncthreads();
    float outv = bm2[h] + h2;
    for (int j = 0; j < 2*HID; ++j) outv += hls[g][j]*w2[j*HID + h];
    Hn[(size_t)(b*NN + s)*HID + h] = outv;
}

// ---------------------------------------------------------------------------
// GAT
// ---------------------------------------------------------------------------
__device__ __forceinline__ void edge_decode(const int* __restrict__ ei, int e,
                                            int& src, int& dst, bool& dropped)
{
    if (e < NEDGEB){
        const int bb = e >> 15, k = e & (NEDGE-1);
        const int s0 = ei[k], d0 = ei[NEDGE + k];
        src = s0 + bb*NN; dst = d0 + bb*NN;
        dropped = (s0 == d0);     // PyG removes pre-existing self loops
    } else { src = dst = e - NEDGEB; dropped = false; }
}

__global__ void k_gat1_lin(const float* __restrict__ Hn, const float* __restrict__ W,
                           const float* __restrict__ asrc, const float* __restrict__ adst,
                           bf16* __restrict__ hw, float* __restrict__ als, float* __restrict__ ald)
{
    const int nid = blockIdx.x, c = threadIdx.x;   // 128
    __shared__ float hr[HID], r1[HID], r2[HID];
    hr[c] = Hn[(size_t)nid*HID + c];
    __syncthreads();
    float a = 0.f;
    for (int k = 0; k < HID; ++k) a += hr[k]*W[k*HID + c];
    hw[(size_t)nid*HID + c] = f2b(a);
    r1[c] = a*asrc[c]; r2[c] = a*adst[c];
    __syncthreads();
    for (int st = 16; st > 0; st >>= 1){
        if ((c & 31) < st){ r1[c] += r1[c+st]; r2[c] += r2[c+st]; }
        __syncthreads();
    }
    if ((c & 31) == 0){
        als[nid*NHEADS + (c>>5)] = r1[c];
        ald[nid*NHEADS + (c>>5)] = r2[c];
    }
}

__global__ void k_gat_edge1(const int* __restrict__ ei, const float* __restrict__ als,
                            const float* __restrict__ ald, bf16* __restrict__ ex,
                            float* __restrict__ denom)
{
    const int idx = blockIdx.x*blockDim.x + threadIdx.x;
    if (idx >= NETOT*NHEADS) return;
    const int e = idx >> 2, hd = idx & 3;
    int src, dst; bool drop;
    edge_decode(ei, e, src, dst, drop);
    if (drop){ ex[idx] = f2b(0.f); return; }
    float a = als[src*NHEADS + hd] + ald[dst*NHEADS + hd];
    a = a > 0.f ? a : 0.2f*a;
    const bf16 vb = f2b(__expf(a));
    ex[idx] = vb;
    atomicAdd(&denom[dst*NHEADS + hd], b2f(vb));
}

__global__ void k_gat_agg1(const int* __restrict__ ei, const bf16* __restrict__ ex,
                           const float* __restrict__ denom, const bf16* __restrict__ hw,
                           float* __restrict__ agg)
{
    const int t = blockIdx.x*blockDim.x + threadIdx.x;   // NETOT*128
    const int e = t >> 7, c = t & 127;
    if (e >= NETOT) return;
    const float x = b2f(ex[e*NHEADS + (c>>5)]);
    if (x == 0.f) return;
    int src, dst; bool drop;
    edge_decode(ei, e, src, dst, drop);
    const float w = x / denom[dst*NHEADS + (c>>5)];
    atomicAdd(&agg[(size_t)dst*HID + c], w * b2f(hw[(size_t)src*HID + c]));
}

__global__ void k_gat1_fin(const float* __restrict__ agg, const float* __restrict__ bias,
                           bf16* __restrict__ g1)
{
    const int t = blockIdx.x*blockDim.x + threadIdx.x;
    if (t >= NNODE*HID) return;
    const float v = agg[t] + bias[t & 127];
    g1[t] = f2b(v > 0.f ? v : expm1f(v));    // elu
}

__global__ void k_gat2_lin(const bf16* __restrict__ g1, const float* __restrict__ W,
                           const float* __restrict__ asrc, const float* __restrict__ adst,
                           bf16* __restrict__ hw2, float* __restrict__ al2s, float* __restrict__ al2d)
{
    const int nid = blockIdx.x, c = threadIdx.x;    // 64 threads = 1 wave
    __shared__ float hr[HID];
    hr[c] = b2f(g1[(size_t)nid*HID + c]);
    hr[c+64] = b2f(g1[(size_t)nid*HID + c + 64]);
    __syncthreads();
    float a = 0.f;
    for (int k = 0; k < HID; ++k) a += hr[k]*W[k*OUTCH + c];
    hw2[(size_t)nid*OUTCH + c] = f2b(a);
    float s1 = a*asrc[c], s2 = a*adst[c];
    #pragma unroll
    for (int off = 32; off > 0; off >>= 1){
        s1 += __shfl_down(s1, off);
        s2 += __shfl_down(s2, off);
    }
    if (c == 0){ al2s[nid] = s1; al2d[nid] = s2; }
}

__global__ void k_gat_edge2(const int* __restrict__ ei, const float* __restrict__ als,
                            const float* __restrict__ ald, bf16* __restrict__ ex,
                            float* __restrict__ denom)
{
    const int e = blockIdx.x*blockDim.x + threadIdx.x;
    if (e >= NETOT) return;
    int src, dst; bool drop;
    edge_decode(ei, e, src, dst, drop);
    if (drop){ ex[e] = f2b(0.f); return; }
    float a = als[src] + ald[dst];
    a = a > 0.f ? a : 0.2f*a;
    const bf16 vb = f2b(__expf(a));
    ex[e] = vb;
    atomicAdd(&denom[dst], b2f(vb));
}

__global__ void k_gat_agg2(const int* __restrict__ ei, const bf16* __restrict__ ex,
                           const float* __restrict__ denom, const bf16* __restrict__ hw2,
                           float* __restrict__ agg)
{
    const int t = blockIdx.x*blockDim.x + threadIdx.x;   // NETOT*64
    const int e = t >> 6, c = t & 63;
    if (e >= NETOT) return;
    const float x = b2f(ex[e]);
    if (x == 0.f) return;
    int src, dst; bool drop;
    edge_decode(ei, e, src, dst, drop);
    const float w = x / denom[dst];
    atomicAdd(&agg[(size_t)dst*OUTCH + c], w * b2f(hw2[(size_t)src*OUTCH + c]));
}

__global__ void k_final(const float* __restrict__ agg2, const float* __restrict__ g2b,
                        const float* __restrict__ fw, const float* __restrict__ fb,
                        float* __restrict__ out)
{
    const int nid = blockIdx.x, c = threadIdx.x;    // 64
    __shared__ float g[OUTCH];
    g[c] = agg2[(size_t)nid*OUTCH + c] + g2b[c];
    __syncthreads();
    if (c < OUTF){
        float o = fb[c];
        for (int k = 0; k < OUTCH; ++k) o += g[k]*fw[k*OUTF + c];
        const int b = nid >> 11, n = nid & (NN-1);
        out[((size_t)b*OUTF + c)*NN + n] = o;
    }
}

// ---------------------------------------------------------------------------
extern "C" void kernel_launch(void* const* d_in, const int* in_sizes, int n_in,
                              void* d_out, int out_size, void* d_ws, size_t ws_size,
                              hipStream_t stream)
{
    const float* x    = (const float*)d_in[0];
    const int*  ei    = (const int*)d_in[1];
    const float* ln1g = (const float*)d_in[2];  const float* ln1b = (const float*)d_in[3];
    const float* t_wq = (const float*)d_in[4];  const float* t_bq = (const float*)d_in[5];
    const float* t_wk = (const float*)d_in[6];  const float* t_bk = (const float*)d_in[7];
    const float* t_wv = (const float*)d_in[8];  const float* t_bv = (const float*)d_in[9];
    const float* t_wo = (const float*)d_in[10]; const float* t_bo = (const float*)d_in[11];
    const float* skw  = (const float*)d_in[12]; const float* skb  = (const float*)d_in[13];
    const float* ln2g = (const float*)d_in[14]; const float* ln2b = (const float*)d_in[15];
    const float* s_wq = (const float*)d_in[16]; const float* s_bq = (const float*)d_in[17];
    const float* s_wk = (const float*)d_in[18]; const float* s_bk = (const float*)d_in[19];
    const float* s_wv = (const float*)d_in[20]; const float* s_bv = (const float*)d_in[21];
    const float* s_wo = (const float*)d_in[22]; const float* s_bo = (const float*)d_in[23];
    const float* ln3g = (const float*)d_in[24]; const float* ln3b = (const float*)d_in[25];
    const float* w1   = (const float*)d_in[26]; const float* b1   = (const float*)d_in[27];
    const float* w2   = (const float*)d_in[28]; const float* b2   = (const float*)d_in[29];
    const float* g1w  = (const float*)d_in[30];
    const float* g1as = (const float*)d_in[31]; const float* g1ad = (const float*)d_in[32];
    const float* g1b  = (const float*)d_in[33];
    const float* g2w  = (const float*)d_in[34];
    const float* g2as = (const float*)d_in[35]; const float* g2ad = (const float*)d_in[36];
    const float* g2b  = (const float*)d_in[37];
    const float* ffw  = (const float*)d_in[38]; const float* ffb  = (const float*)d_in[39];
    float* out = (float*)d_out;

    const size_t MiB = 1024u*1024u;
    const bool wide = ws_size >= 52*MiB;   // K(16)+Vt(16)+CXH1(16)+Hn(4)

    char* base = (char*)d_ws;
    bf16 *Kb, *Vtb, *CXH1;
    float* Hn;
    char* gat_base;
    if (wide){
        Kb   = (bf16*)(base + 0*MiB);      // 16 MiB (all 32 slices, row-major)
        Vtb  = (bf16*)(base + 16*MiB);     // 16 MiB ([slice][kt][ch][32])
        CXH1 = (bf16*)(base + 32*MiB);     // 16 MiB (CX then H1, in place)
        Hn   = (float*)(base + 48*MiB);    // 4 MiB
        gat_base = base;                   // aliases Kb/Vtb (dead after k_h1)
    } else {
        CXH1 = (bf16*)(base + 0*MiB);      // 16 MiB
        Hn   = (float*)(base + 16*MiB);    // 4 MiB
        Kb   = (bf16*)(base + 20*MiB);     // 0.5 MiB (one slice)
        Vtb  = (bf16*)(base + 20*MiB + 512u*1024u);
        gat_base = base;                   // aliases CXH1 (dead after k_mix)
    }
    // GAT scratch (~12.9 MiB) inside gat_base
    char* w = gat_base;
    auto alloc = [&](size_t bytes){ void* p = (void*)w; w += (bytes + 255) & ~(size_t)255; return p; };
    bf16*  hw1  = (bf16*) alloc((size_t)NNODE*HID*sizeof(bf16));
    float* als1 = (float*)alloc((size_t)NNODE*NHEADS*sizeof(float));
    float* ald1 = (float*)alloc((size_t)NNODE*NHEADS*sizeof(float));
    bf16*  ex1  = (bf16*) alloc((size_t)NETOT*NHEADS*sizeof(bf16));
    float* den1 = (float*)alloc((size_t)NNODE*NHEADS*sizeof(float));
    float* agg1 = (float*)alloc((size_t)NNODE*HID*sizeof(float));
    bf16*  g1o  = (bf16*) alloc((size_t)NNODE*HID*sizeof(bf16));
    bf16*  hw2  = (bf16*) alloc((size_t)NNODE*OUTCH*sizeof(bf16));
    float* als2 = (float*)alloc((size_t)NNODE*sizeof(float));
    float* ald2 = (float*)alloc((size_t)NNODE*sizeof(float));
    bf16*  ex2  = (bf16*) alloc((size_t)NETOT*sizeof(bf16));
    float* den2 = (float*)alloc((size_t)NNODE*sizeof(float));
    float* agg2 = (float*)alloc((size_t)NNODE*OUTCH*sizeof(float));

    // ---- trunk ----
    if (wide){
        k_kv<<<PROWS, HID, 0, stream>>>(x, ln1g, ln1b, t_wk, t_bk, t_wv, t_bv, 0, Kb, Vtb);
        k_attn_mfma<<<dim3(BM, NTILE), 256, 0, stream>>>(x, Kb, Vtb, ln1g, ln1b,
                                                         t_wq, t_bq, 0, CXH1);
        k_h1<<<dim3(BM, NTILE), 256, 0, stream>>>(x, t_wo, skw, t_bo, skb, 0, CXH1);
    } else {
        for (int s = 0; s < BM; ++s){
            k_kv<<<NN, HID, 0, stream>>>(x, ln1g, ln1b, t_wk, t_bk, t_wv, t_bv, s*NN, Kb, Vtb);
            k_attn_mfma<<<dim3(1, NTILE), 256, 0, stream>>>(x, Kb, Vtb, ln1g, ln1b,
                                                            t_wq, t_bq, s, CXH1);
        }
        k_h1<<<dim3(BM, NTILE), 256, 0, stream>>>(x, t_wo, skw, t_bo, skb, 0, CXH1);
    }
    k_mix<<<NNODE/4, 512, 0, stream>>>(CXH1, ln2g, ln2b, s_wq, s_bq, s_wk, s_bk,
                                       s_wv, s_bv, s_wo, s_bo, ln3g, ln3b,
                                       w1, b1, w2, b2, Hn);

    // ---- GAT (accumulators zeroed after k_mix; region was dead/poisoned) ----
    hipMemsetAsync(den1, 0, (size_t)NNODE*NHEADS*sizeof(float), stream);
    hipMemsetAsync(agg1, 0, (size_t)NNODE*HID*sizeof(float), stream);
    hipMemsetAsync(den2, 0, (size_t)NNODE*sizeof(float), stream);
    hipMemsetAsync(agg2, 0, (size_t)NNODE*OUTCH*sizeof(float), stream);

    k_gat1_lin<<<NNODE, HID, 0, stream>>>(Hn, g1w, g1as, g1ad, hw1, als1, ald1);
    k_gat_edge1<<<(NETOT*NHEADS + 255)/256, 256, 0, stream>>>(ei, als1, ald1, ex1, den1);
    k_gat_agg1<<<(NETOT*HID)/256, 256, 0, stream>>>(ei, ex1, den1, hw1, agg1);
    k_gat1_fin<<<(NNODE*HID)/256, 256, 0, stream>>>(agg1, g1b, g1o);
    k_gat2_lin<<<NNODE, OUTCH, 0, stream>>>(g1o, g2w, g2as, g2ad, hw2, als2, ald2);
    k_gat_edge2<<<(NETOT + 255)/256, 256, 0, stream>>>(ei, als2, ald2, ex2, den2);
    k_gat_agg2<<<(NETOT*OUTCH)/256, 256, 0, stream>>>(ei, ex2, den2, hw2, agg2);
    k_final<<<NNODE, OUTCH, 0, stream>>>(agg2, g2b, ffw, ffb, out);
}